// Round 6
// baseline (876.287 us; speedup 1.0000x reference)
//
#include <hip/hip_runtime.h>
#include <math.h>

// ---------------------------------------------------------------------------
// GraphMixer forward, round 6:
//   - attnpool_k: attn GEMM (tanh|sigmoid) + gating dot + softmax-weighted
//     H-sum fully fused; per-block slot partials; final2_k reduces + head
//   - rgemm_k / gat3_k unchanged from R5 (proven)
// ---------------------------------------------------------------------------

#define D 128
#define NBLK 3

typedef __attribute__((ext_vector_type(8))) short bf16x8;
typedef __attribute__((ext_vector_type(4))) float f32x4;

static __device__ __forceinline__ float bf2f(unsigned short u) {
    union { unsigned i; float f; } c; c.i = ((unsigned)u) << 16; return c.f;
}
static __device__ __forceinline__ unsigned short f2bf(float f) {
    union { float f; unsigned i; } c; c.f = f;
    unsigned r = c.i + 0x7fff + ((c.i >> 16) & 1);
    return (unsigned short)(r >> 16);
}

static __device__ __forceinline__ void gl16(const unsigned short* g, unsigned short* l) {
    __builtin_amdgcn_global_load_lds((const __attribute__((address_space(1))) void*)g,
                                     (__attribute__((address_space(3))) void*)l, 16, 0, 0);
}

// ---------------- CSR build ----------------
__global__ void zero_k(int* deg, int* fill, int n) {
    int i = blockIdx.x * blockDim.x + threadIdx.x;
    if (i < n) { deg[i] = 0; fill[i] = 0; }
}

__global__ void hist_k(const int* __restrict__ dst, int* __restrict__ deg, int E) {
    int e = blockIdx.x * blockDim.x + threadIdx.x;
    if (e < E) atomicAdd(&deg[dst[e]], 1);
}

__global__ __launch_bounds__(256) void blockscan_k(const int* __restrict__ deg,
                                                   int* __restrict__ rowptr,
                                                   int* __restrict__ bsum, int n) {
    __shared__ int tmp[256];
    const int tid = threadIdx.x;
    const int i = blockIdx.x * 256 + tid;
    int v = (i < n) ? deg[i] : 0;
    tmp[tid] = v;
    __syncthreads();
#pragma unroll
    for (int off = 1; off < 256; off <<= 1) {
        int t = (tid >= off) ? tmp[tid - off] : 0;
        __syncthreads();
        tmp[tid] += t;
        __syncthreads();
    }
    if (i < n) rowptr[i + 1] = tmp[tid];
    if (tid == 255) bsum[blockIdx.x] = tmp[255];
}

__global__ __launch_bounds__(256) void scansums_k(int* __restrict__ bsum, int nb) {
    __shared__ int tmp[256];
    const int tid = threadIdx.x;
    int v = (tid < nb) ? bsum[tid] : 0;
    tmp[tid] = v;
    __syncthreads();
#pragma unroll
    for (int off = 1; off < 256; off <<= 1) {
        int t = (tid >= off) ? tmp[tid - off] : 0;
        __syncthreads();
        tmp[tid] += t;
        __syncthreads();
    }
    if (tid < nb) bsum[tid] = tmp[tid];
}

__global__ __launch_bounds__(256) void addoff_k(int* __restrict__ rowptr,
                                                const int* __restrict__ bsum, int n) {
    int i = blockIdx.x * 256 + threadIdx.x;
    if (i == 0) rowptr[0] = 0;
    if (i < n && blockIdx.x > 0) rowptr[i + 1] += bsum[blockIdx.x - 1];
}

__global__ void scatter_k(const int* __restrict__ src, const int* __restrict__ dst,
                          const int* __restrict__ rowptr, int* __restrict__ fill,
                          int* __restrict__ esrc, int E) {
    int e = blockIdx.x * blockDim.x + threadIdx.x;
    if (e < E) {
        int d = dst[e];
        int pos = rowptr[d] + atomicAdd(&fill[d], 1);
        esrc[pos] = src[e];
    }
}

// ---------------- weight prep: [K][M] f32 -> chunked bf16 fragment order ----
struct WDesc { const float* s; unsigned short* d; int K; int M; };
struct WPack { WDesc w[21]; };

__global__ __launch_bounds__(256) void wprep_k(WPack p) {
    WDesc d = p.w[blockIdx.y];
    const int nc = d.K / 32;
    const int chunks = (d.M / 16) * nc * 64;
    for (int i = blockIdx.x * 256 + threadIdx.x; i < chunks; i += gridDim.x * 256) {
        const int l = i & 63;
        const int c = (i >> 6) % nc;
        const int t = i / (64 * nc);
        const int m = t * 16 + (l & 15);
        const int kb = c * 32 + ((l >> 4) & 3) * 8;
#pragma unroll
        for (int j = 0; j < 8; ++j)
            d.d[(size_t)i * 8 + j] = f2bf(d.s[(size_t)(kb + j) * d.M + m]);
    }
}

// stacked biases: sb[i][256] = [bl_i | br_i] (i<3), sb[3][256] = [ba | bb]
__global__ __launch_bounds__(256) void bcat_k(const float* bl, const float* br,
                                              const float* ba, const float* bb,
                                              float* sb) {
    const int t = threadIdx.x;
    for (int i = 0; i < 3; ++i)
        sb[i * 256 + t] = (t < 128) ? bl[i * 128 + t] : br[i * 128 + t - 128];
    sb[3 * 256 + t] = (t < 128) ? ba[t] : bb[t - 128];
}

// ---------------- B-resident MFMA GEMM, in-kernel round loop ----------------
template <int NR, bool KM, int ACT, bool BIAS, bool ACC, bool LNM, bool A16,
          bool W32, bool W16>
__global__ __launch_bounds__(256) void rgemm_k(const void* __restrict__ Ap,
                                               const unsigned short* __restrict__ BTc,
                                               const float* __restrict__ bias,
                                               const float* __restrict__ lng,
                                               const float* __restrict__ lnb,
                                               float* __restrict__ C32,
                                               unsigned short* __restrict__ C16,
                                               int N, int strideA, int M) {
    __shared__ unsigned short Bls[128 * 128];   // 32 KB
    const int tid = threadIdx.x;
    const int w = tid >> 6, l = tid & 63;
    const int q = l >> 4;
    int r = blockIdx.x * 64 + w * 16 + (l & 15);
    if (r > N - 1) r = N - 1;

    bf16x8 afr[4];
    auto loadA = [&](int koff) {
        if (A16) {
            const unsigned short* A = (const unsigned short*)Ap;
#pragma unroll
            for (int c = 0; c < 4; ++c)
                afr[c] = *(const bf16x8*)(A + (size_t)r * strideA + koff + c * 32 + q * 8);
        } else {
            const float* A = (const float*)Ap;
            float av[4][8];
#pragma unroll
            for (int c = 0; c < 4; ++c) {
                const float* ap = A + (size_t)r * strideA + koff + c * 32 + q * 8;
                const float4 v0 = *(const float4*)ap;
                const float4 v1 = *(const float4*)(ap + 4);
                av[c][0] = v0.x; av[c][1] = v0.y; av[c][2] = v0.z; av[c][3] = v0.w;
                av[c][4] = v1.x; av[c][5] = v1.y; av[c][6] = v1.z; av[c][7] = v1.w;
            }
            if (LNM) {
                float s = 0.f;
#pragma unroll
                for (int c = 0; c < 4; ++c)
#pragma unroll
                    for (int j = 0; j < 8; ++j) s += av[c][j];
                s += __shfl_xor(s, 16, 64); s += __shfl_xor(s, 32, 64);
                const float mu = s * (1.f / 128.f);
                float vv = 0.f;
#pragma unroll
                for (int c = 0; c < 4; ++c)
#pragma unroll
                    for (int j = 0; j < 8; ++j) { const float dd = av[c][j] - mu; vv += dd * dd; }
                vv += __shfl_xor(vv, 16, 64); vv += __shfl_xor(vv, 32, 64);
                const float rs = rsqrtf(vv * (1.f / 128.f) + 1e-5f);
#pragma unroll
                for (int c = 0; c < 4; ++c) {
                    const int kb = c * 32 + q * 8;
                    const float4 g0 = *(const float4*)(lng + kb);
                    const float4 g1 = *(const float4*)(lng + kb + 4);
                    const float4 b0 = *(const float4*)(lnb + kb);
                    const float4 b1 = *(const float4*)(lnb + kb + 4);
                    const float gg[8] = {g0.x, g0.y, g0.z, g0.w, g1.x, g1.y, g1.z, g1.w};
                    const float bb[8] = {b0.x, b0.y, b0.z, b0.w, b1.x, b1.y, b1.z, b1.w};
#pragma unroll
                    for (int j = 0; j < 8; ++j)
                        av[c][j] = (av[c][j] - mu) * rs * gg[j] + bb[j];
                }
            }
#pragma unroll
            for (int c = 0; c < 4; ++c)
#pragma unroll
                for (int j = 0; j < 8; ++j) afr[c][j] = (short)f2bf(av[c][j]);
        }
    };

    f32x4 acc[8];
#pragma unroll
    for (int t = 0; t < 8; ++t) acc[t] = (f32x4){0.f, 0.f, 0.f, 0.f};

    if (!KM) loadA(0);

    const int rb = blockIdx.x * 64 + w * 16 + q * 4;
    auto epi = [&](int col0) {
#pragma unroll
        for (int t = 0; t < 8; ++t) {
            const int col = col0 + t * 16 + (l & 15);
            const float bv = BIAS ? bias[col] : 0.f;
#pragma unroll
            for (int rr = 0; rr < 4; ++rr) {
                const int row = rb + rr;
                if (row >= N) continue;
                float xv = acc[t][rr] + bv;
                if (ACC) xv += C32[(size_t)row * M + col];
                if (ACT == 1) xv = fmaxf(xv, 0.f);
                else if (ACT == 2) xv = 0.5f * xv * (1.f + erff(xv * 0.70710678118654752f));
                if (W32) C32[(size_t)row * M + col] = xv;
                if (W16) C16[(size_t)row * M + col] = f2bf(xv);
            }
        }
    };

#pragma unroll
    for (int rnd = 0; rnd < NR; ++rnd) {
        if (rnd) __syncthreads();
        const unsigned short* bsrc = BTc + (size_t)rnd * 16384;
#pragma unroll
        for (int i = 0; i < 8; ++i) {
            const int idx = i * 256 + tid;
            gl16(bsrc + (size_t)idx * 8, &Bls[idx * 8]);
        }
        if (KM) loadA(rnd * 128);
        __syncthreads();
#pragma unroll
        for (int c = 0; c < 4; ++c)
#pragma unroll
            for (int t = 0; t < 8; ++t) {
                const bf16x8 bfr = *(const bf16x8*)&Bls[((t * 4 + c) * 64 + l) * 8];
                acc[t] = __builtin_amdgcn_mfma_f32_16x16x32_bf16(afr[c], bfr, acc[t], 0, 0, 0);
            }
        if (!KM) {
            epi(rnd * 128);
#pragma unroll
            for (int t = 0; t < 8; ++t) acc[t] = (f32x4){0.f, 0.f, 0.f, 0.f};
        }
    }
    if (KM) epi(0);
}

// ------- GATv2: quarter-wave per edge, max-free softmax, SW pipeline --------
__global__ __launch_bounds__(256) void gat3_k(const unsigned short* __restrict__ X,
                                              const float* __restrict__ att,
                                              const float* __restrict__ gbias,
                                              const int* __restrict__ rowptr,
                                              const int* __restrict__ esrc,
                                              float* __restrict__ H, int n) {
    const int l = threadIdx.x & 63;
    const int node = blockIdx.x * 4 + (threadIdx.x >> 6);
    if (node >= n) return;
    const int q = l >> 4;
    const int d0 = (l & 15) * 8;

    float a8[8], xr[8], xs[8];
    {
        const float4 t0 = *(const float4*)&att[d0];
        const float4 t1 = *(const float4*)&att[d0 + 4];
        a8[0] = t0.x; a8[1] = t0.y; a8[2] = t0.z; a8[3] = t0.w;
        a8[4] = t1.x; a8[5] = t1.y; a8[6] = t1.z; a8[7] = t1.w;
        const bf16x8 uxs = *(const bf16x8*)&X[(size_t)node * 256 + d0];
        const bf16x8 uxr = *(const bf16x8*)&X[(size_t)node * 256 + 128 + d0];
#pragma unroll
        for (int j = 0; j < 8; ++j) {
            xs[j] = bf2f((unsigned short)uxs[j]);
            xr[j] = bf2f((unsigned short)uxr[j]);
        }
    }

    float sc = 0.f;
#pragma unroll
    for (int j = 0; j < 8; ++j) {
        const float e = xs[j] + xr[j];
        sc = fmaf(a8[j], fmaxf(e, 0.2f * e), sc);
    }
#pragma unroll
    for (int m = 1; m < 16; m <<= 1) sc += __shfl_xor(sc, m, 64);
    const float wself = __expf(sc);
    float dsum = (q == 0) ? wself : 0.f;
    float acc[8];
#pragma unroll
    for (int j = 0; j < 8; ++j) acc[j] = (q == 0) ? wself * xs[j] : 0.f;

    const int p1 = rowptr[node + 1];
    int p = rowptr[node] + q;
    bool v0 = p < p1, v1 = p + 4 < p1, v2 = p + 8 < p1;
    int i2 = v2 ? esrc[p + 8] : 0;
    bf16x8 u0, u1;
    if (v0) u0 = *(const bf16x8*)&X[(size_t)esrc[p] * 256 + d0];
    if (v1) u1 = *(const bf16x8*)&X[(size_t)esrc[p + 4] * 256 + d0];
    while (v0) {
        bf16x8 u2;
        if (v2) u2 = *(const bf16x8*)&X[(size_t)i2 * 256 + d0];
        const bool v3 = p + 12 < p1;
        const int i3 = v3 ? esrc[p + 12] : 0;

        float xl[8];
#pragma unroll
        for (int j = 0; j < 8; ++j) xl[j] = bf2f((unsigned short)u0[j]);
        float e_sc = 0.f;
#pragma unroll
        for (int j = 0; j < 8; ++j) {
            const float e = xl[j] + xr[j];
            e_sc = fmaf(a8[j], fmaxf(e, 0.2f * e), e_sc);
        }
#pragma unroll
        for (int m = 1; m < 16; m <<= 1) e_sc += __shfl_xor(e_sc, m, 64);
        const float wgt = __expf(e_sc);
        dsum += wgt;
#pragma unroll
        for (int j = 0; j < 8; ++j) acc[j] = fmaf(wgt, xl[j], acc[j]);

        u0 = u1; u1 = u2; i2 = i3;
        v0 = v1; v1 = v2; v2 = v3;
        p += 4;
    }

#pragma unroll
    for (int m = 16; m < 64; m <<= 1) {
        dsum += __shfl_xor(dsum, m, 64);
#pragma unroll
        for (int j = 0; j < 8; ++j) acc[j] += __shfl_xor(acc[j], m, 64);
    }

    if (q == 0) {
        const float inv = 1.f / dsum;
        const size_t o = (size_t)node * D + d0;
        float4 h0 = *(const float4*)&H[o];
        float4 h1 = *(const float4*)&H[o + 4];
        float hv[8] = {h0.x, h0.y, h0.z, h0.w, h1.x, h1.y, h1.z, h1.w};
#pragma unroll
        for (int j = 0; j < 8; ++j) hv[j] += acc[j] * inv + gbias[d0 + j];
        *(float4*)&H[o]     = make_float4(hv[0], hv[1], hv[2], hv[3]);
        *(float4*)&H[o + 4] = make_float4(hv[4], hv[5], hv[6], hv[7]);
    }
}

// ------- fused attention pooling: GEMM + gating + weighted H-sum ------------
// BTc = [Wa|Wb] chunked blobs; bias = [ba|bb]; per-block partial -> slot
__global__ __launch_bounds__(256) void attnpool_k(const float* __restrict__ H,
                                                  const unsigned short* __restrict__ BTc,
                                                  const float* __restrict__ bias,
                                                  const float* __restrict__ Wc,
                                                  const float* __restrict__ bc,
                                                  float* __restrict__ slot, int N) {
    __shared__ unsigned short Bls[128 * 128];   // 32 KB
    __shared__ float sacc[4][128];
    __shared__ float sdn[4];
    const int tid = threadIdx.x;
    const int w = tid >> 6, l = tid & 63;
    const int q = l >> 4, l15 = l & 15;
    const int rowbase = blockIdx.x * 64 + w * 16;
    int r = rowbase + l15;
    if (r > N - 1) r = N - 1;

    // H row fragments: fp32 kept for the weighted sum, bf16 for MFMA
    float av[4][8];
    bf16x8 afr[4];
#pragma unroll
    for (int c = 0; c < 4; ++c) {
        const float* ap = H + (size_t)r * D + c * 32 + q * 8;
        const float4 v0 = *(const float4*)ap;
        const float4 v1 = *(const float4*)(ap + 4);
        av[c][0] = v0.x; av[c][1] = v0.y; av[c][2] = v0.z; av[c][3] = v0.w;
        av[c][4] = v1.x; av[c][5] = v1.y; av[c][6] = v1.z; av[c][7] = v1.w;
#pragma unroll
        for (int j = 0; j < 8; ++j) afr[c][j] = (short)f2bf(av[c][j]);
    }

    float th[8][4];   // stashed tanh values (round 0)
    f32x4 acc[8];

#pragma unroll
    for (int rnd = 0; rnd < 2; ++rnd) {
        if (rnd) __syncthreads();
        const unsigned short* bsrc = BTc + (size_t)rnd * 16384;
#pragma unroll
        for (int i = 0; i < 8; ++i) {
            const int idx = i * 256 + tid;
            gl16(bsrc + (size_t)idx * 8, &Bls[idx * 8]);
        }
#pragma unroll
        for (int t = 0; t < 8; ++t) acc[t] = (f32x4){0.f, 0.f, 0.f, 0.f};
        __syncthreads();
#pragma unroll
        for (int c = 0; c < 4; ++c)
#pragma unroll
            for (int t = 0; t < 8; ++t) {
                const bf16x8 bfr = *(const bf16x8*)&Bls[((t * 4 + c) * 64 + l) * 8];
                acc[t] = __builtin_amdgcn_mfma_f32_16x16x32_bf16(afr[c], bfr, acc[t], 0, 0, 0);
            }
        if (rnd == 0) {
#pragma unroll
            for (int t = 0; t < 8; ++t) {
                const float bv = bias[t * 16 + l15];
#pragma unroll
                for (int rr = 0; rr < 4; ++rr) th[t][rr] = tanhf(acc[t][rr] + bv);
            }
        }
    }

    // gating dot: pa[rr] = sum_col tanh*sigmoid*Wc
    float pa[4] = {0.f, 0.f, 0.f, 0.f};
#pragma unroll
    for (int t = 0; t < 8; ++t) {
        const float bv = bias[128 + t * 16 + l15];
        const float wcv = Wc[t * 16 + l15];
#pragma unroll
        for (int rr = 0; rr < 4; ++rr) {
            const float sg = 1.f / (1.f + __expf(-(acc[t][rr] + bv)));
            pa[rr] = fmaf(th[t][rr] * sg, wcv, pa[rr]);
        }
    }
#pragma unroll
    for (int m = 1; m < 16; m <<= 1)
#pragma unroll
        for (int rr = 0; rr < 4; ++rr) pa[rr] += __shfl_xor(pa[rr], m, 64);

    const float bcv = bc[0];
    float wgt[4];
#pragma unroll
    for (int rr = 0; rr < 4; ++rr) {
        const int row = blockIdx.x * 64 + w * 16 + q * 4 + rr;
        wgt[rr] = (row < N) ? __expf(pa[rr] + bcv) : 0.f;
    }
    // denominator: sum over the wave's 16 rows
    float s = wgt[0] + wgt[1] + wgt[2] + wgt[3];
    s += __shfl_xor(s, 16, 64);
    s += __shfl_xor(s, 32, 64);
    if (l == 0) sdn[w] = s;

    // weight for MY H-row (row = rowbase + l15): fetch from quarter l15>>2
    const int srcl = (w << 6) ? 0 : 0;   // (shuffle is intra-wave; src is 0..63)
    const int sl = ((l15 >> 2) << 4);
    float wv[4];
#pragma unroll
    for (int rr = 0; rr < 4; ++rr) wv[rr] = __shfl(wgt[rr], sl, 64);
    const int rsel = l15 & 3;
    float wm = (rsel == 0) ? wv[0] : (rsel == 1) ? wv[1] : (rsel == 2) ? wv[2] : wv[3];

    // weighted H sum: reduce over the 16 rows (l15 lanes)
#pragma unroll
    for (int c = 0; c < 4; ++c) {
        float pv[8];
#pragma unroll
        for (int j = 0; j < 8; ++j) pv[j] = wm * av[c][j];
#pragma unroll
        for (int m = 1; m < 16; m <<= 1)
#pragma unroll
            for (int j = 0; j < 8; ++j) pv[j] += __shfl_xor(pv[j], m, 64);
        if (l15 == 0) {
#pragma unroll
            for (int j = 0; j < 8; ++j) sacc[w][c * 32 + q * 8 + j] = pv[j];
        }
    }
    __syncthreads();
    if (tid < 128) {
        const float tot = sacc[0][tid] + sacc[1][tid] + sacc[2][tid] + sacc[3][tid];
        slot[(size_t)blockIdx.x * 132 + tid] = tot;
    }
    if (tid == 0)
        slot[(size_t)blockIdx.x * 132 + 128] = sdn[0] + sdn[1] + sdn[2] + sdn[3];
}

// ---------------- final: slot reduce + rho/cls head ----------------
__global__ __launch_bounds__(128) void final2_k(const float* __restrict__ slot, int nb,
                                                const float* __restrict__ rho_W,
                                                const float* __restrict__ rho_b,
                                                const float* __restrict__ cls_W,
                                                const float* __restrict__ cls_b,
                                                float* __restrict__ out) {
    __shared__ float hp[128];
    __shared__ float sdn[128];
    __shared__ float hr[128];
    __shared__ float lg[4];
    const int t = threadIdx.x;
    float a = 0.f, d = 0.f;
    for (int b = 0; b < nb; ++b) a += slot[(size_t)b * 132 + t];
    for (int b = t; b < nb; b += 128) d += slot[(size_t)b * 132 + 128];
    sdn[t] = d;
    __syncthreads();
    for (int s = 64; s > 0; s >>= 1) {
        if (t < s) sdn[t] += sdn[t + s];
        __syncthreads();
    }
    hp[t] = a / sdn[0];
    __syncthreads();
    float s = rho_b[t];
    for (int k = 0; k < 128; ++k) s = fmaf(hp[k], rho_W[k * 128 + t], s);
    hr[t] = fmaxf(s, 0.f);
    __syncthreads();
    if (t < 4) {
        float l = cls_b[t];
        for (int k = 0; k < 128; ++k) l = fmaf(hr[k], cls_W[k * 4 + t], l);
        lg[t] = l;
    }
    __syncthreads();
    if (t == 0) {
        float hz[4], S[4];
        for (int c = 0; c < 4; ++c) hz[c] = 1.f / (1.f + expf(-lg[c]));
        S[0] = 1.f - hz[0];
        for (int c = 1; c < 4; ++c) S[c] = S[c - 1] * (1.f - hz[c]);
        int am = 0; float bm = lg[0];
        for (int c = 1; c < 4; ++c) if (lg[c] > bm) { bm = lg[c]; am = c; }
        out[0] = hz[0]; out[1] = hz[1]; out[2] = hz[2]; out[3] = hz[3];
        out[4] = S[0];  out[5] = S[1];  out[6] = S[2];  out[7] = S[3];
        out[8] = (float)am;
        out[9] = lg[0]; out[10] = lg[1]; out[11] = lg[2]; out[12] = lg[3];
    }
}

// ---------------------------------------------------------------------------
static inline int cdiv(int a, int b) { return (a + b - 1) / b; }

extern "C" void kernel_launch(void* const* d_in, const int* in_sizes, int n_in,
                              void* d_out, int out_size, void* d_ws, size_t ws_size,
                              hipStream_t stream) {
    const float* x      = (const float*)d_in[0];
    const int*   ei     = (const int*)d_in[1];
    const float* emb_W  = (const float*)d_in[2];
    const float* emb_b  = (const float*)d_in[3];
    const float* ln1_g  = (const float*)d_in[4];
    const float* ln1_b  = (const float*)d_in[5];
    const float* gat_Wl = (const float*)d_in[6];
    const float* gat_bl = (const float*)d_in[7];
    const float* gat_Wr = (const float*)d_in[8];
    const float* gat_br = (const float*)d_in[9];
    const float* gat_att  = (const float*)d_in[10];
    const float* gat_bias = (const float*)d_in[11];
    const float* mlp_w1[NBLK] = {(const float*)d_in[12], (const float*)d_in[14], (const float*)d_in[16]};
    const float* mlp_w2[NBLK] = {(const float*)d_in[13], (const float*)d_in[15], (const float*)d_in[17]};
    const float* attn_Wa = (const float*)d_in[18];
    const float* attn_ba = (const float*)d_in[19];
    const float* attn_Wb = (const float*)d_in[20];
    const float* attn_bb = (const float*)d_in[21];
    const float* attn_Wc = (const float*)d_in[22];
    const float* attn_bc = (const float*)d_in[23];
    const float* rho_W   = (const float*)d_in[24];
    const float* rho_b   = (const float*)d_in[25];
    const float* cls_W   = (const float*)d_in[26];
    const float* cls_b   = (const float*)d_in[27];
    float* out = (float*)d_out;

    const int N = in_sizes[0] / 512;   // 50000
    const int E = in_sizes[1] / 2;     // 800000
    const int* src = ei;
    const int* dst = ei + E;
    const int gx = cdiv(N, 64);        // 782

    // ---- workspace layout ----
    char* base = (char*)d_ws;
    float* H = (float*)base;                                    // N*128 f32
    unsigned short* X = (unsigned short*)(H + (size_t)N * D);   // N*256 bf16 [xl|xr]
    unsigned short* T = X + (size_t)N * 256;                    // N*384 bf16
    float* slot = (float*)(T + (size_t)N * 384);                // gx*132
    float* sb   = slot + (size_t)gx * 132;                      // 4*256
    unsigned short* wbuf = (unsigned short*)(sb + 1024);        // 393216 bf16
    int* esrc   = (int*)(wbuf + 393216);                        // E
    int* deg    = esrc + E;                                     // N
    int* rowptr = deg + N;                                      // N+1
    int* fill   = rowptr + N + 1;                               // N
    int* bsum   = fill + N;                                     // 256

    unsigned short* embT = wbuf;                    // 4 rounds
    unsigned short* gatT = wbuf + 4 * 16384;        // 3 layers x 2 (Wl,Wr)
    unsigned short* w1T0 = gatT + 6 * 16384;
    unsigned short* w1T1 = w1T0 + 16384;
    unsigned short* w1T2 = w1T1 + 2 * 16384;
    unsigned short* w2T0 = w1T2 + 3 * 16384;
    unsigned short* w2T1 = w2T0 + 16384;
    unsigned short* w2T2 = w2T1 + 2 * 16384;
    unsigned short* attT = w2T2 + 3 * 16384;        // 2 blobs (Wa,Wb)
    unsigned short* w1T[NBLK] = {w1T0, w1T1, w1T2};
    unsigned short* w2T[NBLK] = {w2T0, w2T1, w2T2};

    // ---- CSR build ----
    const int nb = cdiv(N, 256);
    zero_k<<<cdiv(N, 256), 256, 0, stream>>>(deg, fill, N);
    hist_k<<<cdiv(E, 256), 256, 0, stream>>>(dst, deg, E);
    blockscan_k<<<nb, 256, 0, stream>>>(deg, rowptr, bsum, N);
    scansums_k<<<1, 256, 0, stream>>>(bsum, nb);
    addoff_k<<<nb, 256, 0, stream>>>(rowptr, bsum, N);
    scatter_k<<<cdiv(E, 256), 256, 0, stream>>>(src, dst, rowptr, fill, esrc, E);

    // ---- weight/bias prep ----
    {
        WPack p;
        int di = 0;
        for (int r = 0; r < 4; ++r)
            p.w[di++] = {emb_W + (size_t)r * 128 * 128, embT + (size_t)r * 16384, 128, 128};
        for (int i = 0; i < 3; ++i) {
            p.w[di++] = {gat_Wl + (size_t)i * 16384, gatT + (size_t)(2 * i) * 16384, 128, 128};
            p.w[di++] = {gat_Wr + (size_t)i * 16384, gatT + (size_t)(2 * i + 1) * 16384, 128, 128};
        }
        for (int i = 0; i < 3; ++i)
            p.w[di++] = {mlp_w1[i], w1T[i], 128, 128 * (i + 1)};
        for (int i = 0; i < 3; ++i)
            for (int r = 0; r <= i; ++r)
                p.w[di++] = {mlp_w2[i] + (size_t)r * 128 * 128, w2T[i] + (size_t)r * 16384, 128, 128};
        p.w[di++] = {attn_Wa, attT, 128, 128};
        p.w[di++] = {attn_Wb, attT + 16384, 128, 128};
        wprep_k<<<dim3(32, 21), 256, 0, stream>>>(p);
    }
    bcat_k<<<1, 256, 0, stream>>>(gat_bl, gat_br, attn_ba, attn_bb, sb);

    // ---- embedding: H = relu(x @ emb_W + emb_b), 4 k-rounds ----
    rgemm_k<4, true, 1, true, false, false, false, true, false>
        <<<gx, 256, 0, stream>>>(x, embT, emb_b, nullptr, nullptr,
                                 H, nullptr, N, 512, 128);

    // ---- 3 blocks ----
    for (int i = 0; i < NBLK; ++i) {
        rgemm_k<2, false, 0, true, false, true, false, false, true>
            <<<gx, 256, 0, stream>>>(H, gatT + (size_t)(2 * i) * 16384, sb + i * 256,
                                     ln1_g + i * D, ln1_b + i * D, nullptr, X, N, 128, 256);
        gat3_k<<<cdiv(N, 4), 256, 0, stream>>>(X, gat_att + i * D, gat_bias + i * D,
                                               rowptr, esrc, H, N);
        const int h = D * (i + 1);
        if (i == 0)
            rgemm_k<1, false, 2, false, false, false, false, false, true>
                <<<gx, 256, 0, stream>>>(H, w1T[i], nullptr, nullptr, nullptr,
                                         nullptr, T, N, 128, h);
        else if (i == 1)
            rgemm_k<2, false, 2, false, false, false, false, false, true>
                <<<gx, 256, 0, stream>>>(H, w1T[i], nullptr, nullptr, nullptr,
                                         nullptr, T, N, 128, h);
        else
            rgemm_k<3, false, 2, false, false, false, false, false, true>
                <<<gx, 256, 0, stream>>>(H, w1T[i], nullptr, nullptr, nullptr,
                                         nullptr, T, N, 128, h);
        if (i == 0)
            rgemm_k<1, true, 0, false, true, false, true, true, false>
                <<<gx, 256, 0, stream>>>(T, w2T[i], nullptr, nullptr, nullptr,
                                         H, nullptr, N, h, 128);
        else if (i == 1)
            rgemm_k<2, true, 0, false, true, false, true, true, false>
                <<<gx, 256, 0, stream>>>(T, w2T[i], nullptr, nullptr, nullptr,
                                         H, nullptr, N, h, 128);
        else
            rgemm_k<3, true, 0, false, true, false, true, true, false>
                <<<gx, 256, 0, stream>>>(T, w2T[i], nullptr, nullptr, nullptr,
                                         H, nullptr, N, h, 128);
    }

    // ---- fused gated attention pooling + head ----
    attnpool_k<<<gx, 256, 0, stream>>>(H, attT, sb + 3 * 256, attn_Wc, attn_bc, slot, N);
    final2_k<<<1, 128, 0, stream>>>(slot, gx, rho_W, rho_b, cls_W, cls_b, out);
}

// Round 7
// 702.083 us; speedup vs baseline: 1.2481x; 1.2481x over previous
//
#include <hip/hip_runtime.h>
#include <math.h>

// ---------------------------------------------------------------------------
// GraphMixer forward, round 7:
//   - R6's fused attnpool (GEMM+gating+weighted H-sum) but with ATOMIC
//     accumulation into red[132] (R5-proven pattern) instead of the serial
//     782-slot gather that cost 195 us in R6.
//   - rgemm_k / gat3_k unchanged (proven).
// ---------------------------------------------------------------------------

#define D 128
#define NBLK 3

typedef __attribute__((ext_vector_type(8))) short bf16x8;
typedef __attribute__((ext_vector_type(4))) float f32x4;

static __device__ __forceinline__ float bf2f(unsigned short u) {
    union { unsigned i; float f; } c; c.i = ((unsigned)u) << 16; return c.f;
}
static __device__ __forceinline__ unsigned short f2bf(float f) {
    union { float f; unsigned i; } c; c.f = f;
    unsigned r = c.i + 0x7fff + ((c.i >> 16) & 1);
    return (unsigned short)(r >> 16);
}

static __device__ __forceinline__ void gl16(const unsigned short* g, unsigned short* l) {
    __builtin_amdgcn_global_load_lds((const __attribute__((address_space(1))) void*)g,
                                     (__attribute__((address_space(3))) void*)l, 16, 0, 0);
}

// ---------------- CSR build ----------------
__global__ void zero_k(int* deg, int* fill, float* red, int n) {
    int i = blockIdx.x * blockDim.x + threadIdx.x;
    if (i < n) { deg[i] = 0; fill[i] = 0; }
    if (i < 132) red[i] = 0.f;
}

__global__ void hist_k(const int* __restrict__ dst, int* __restrict__ deg, int E) {
    int e = blockIdx.x * blockDim.x + threadIdx.x;
    if (e < E) atomicAdd(&deg[dst[e]], 1);
}

__global__ __launch_bounds__(256) void blockscan_k(const int* __restrict__ deg,
                                                   int* __restrict__ rowptr,
                                                   int* __restrict__ bsum, int n) {
    __shared__ int tmp[256];
    const int tid = threadIdx.x;
    const int i = blockIdx.x * 256 + tid;
    int v = (i < n) ? deg[i] : 0;
    tmp[tid] = v;
    __syncthreads();
#pragma unroll
    for (int off = 1; off < 256; off <<= 1) {
        int t = (tid >= off) ? tmp[tid - off] : 0;
        __syncthreads();
        tmp[tid] += t;
        __syncthreads();
    }
    if (i < n) rowptr[i + 1] = tmp[tid];
    if (tid == 255) bsum[blockIdx.x] = tmp[255];
}

__global__ __launch_bounds__(256) void scansums_k(int* __restrict__ bsum, int nb) {
    __shared__ int tmp[256];
    const int tid = threadIdx.x;
    int v = (tid < nb) ? bsum[tid] : 0;
    tmp[tid] = v;
    __syncthreads();
#pragma unroll
    for (int off = 1; off < 256; off <<= 1) {
        int t = (tid >= off) ? tmp[tid - off] : 0;
        __syncthreads();
        tmp[tid] += t;
        __syncthreads();
    }
    if (tid < nb) bsum[tid] = tmp[tid];
}

__global__ __launch_bounds__(256) void addoff_k(int* __restrict__ rowptr,
                                                const int* __restrict__ bsum, int n) {
    int i = blockIdx.x * 256 + threadIdx.x;
    if (i == 0) rowptr[0] = 0;
    if (i < n && blockIdx.x > 0) rowptr[i + 1] += bsum[blockIdx.x - 1];
}

__global__ void scatter_k(const int* __restrict__ src, const int* __restrict__ dst,
                          const int* __restrict__ rowptr, int* __restrict__ fill,
                          int* __restrict__ esrc, int E) {
    int e = blockIdx.x * blockDim.x + threadIdx.x;
    if (e < E) {
        int d = dst[e];
        int pos = rowptr[d] + atomicAdd(&fill[d], 1);
        esrc[pos] = src[e];
    }
}

// ---------------- weight prep: [K][M] f32 -> chunked bf16 fragment order ----
struct WDesc { const float* s; unsigned short* d; int K; int M; };
struct WPack { WDesc w[21]; };

__global__ __launch_bounds__(256) void wprep_k(WPack p) {
    WDesc d = p.w[blockIdx.y];
    const int nc = d.K / 32;
    const int chunks = (d.M / 16) * nc * 64;
    for (int i = blockIdx.x * 256 + threadIdx.x; i < chunks; i += gridDim.x * 256) {
        const int l = i & 63;
        const int c = (i >> 6) % nc;
        const int t = i / (64 * nc);
        const int m = t * 16 + (l & 15);
        const int kb = c * 32 + ((l >> 4) & 3) * 8;
#pragma unroll
        for (int j = 0; j < 8; ++j)
            d.d[(size_t)i * 8 + j] = f2bf(d.s[(size_t)(kb + j) * d.M + m]);
    }
}

// stacked biases: sb[i][256] = [bl_i | br_i] (i<3), sb[3][256] = [ba | bb]
__global__ __launch_bounds__(256) void bcat_k(const float* bl, const float* br,
                                              const float* ba, const float* bb,
                                              float* sb) {
    const int t = threadIdx.x;
    for (int i = 0; i < 3; ++i)
        sb[i * 256 + t] = (t < 128) ? bl[i * 128 + t] : br[i * 128 + t - 128];
    sb[3 * 256 + t] = (t < 128) ? ba[t] : bb[t - 128];
}

// ---------------- B-resident MFMA GEMM, in-kernel round loop ----------------
template <int NR, bool KM, int ACT, bool BIAS, bool ACC, bool LNM, bool A16,
          bool W32, bool W16>
__global__ __launch_bounds__(256) void rgemm_k(const void* __restrict__ Ap,
                                               const unsigned short* __restrict__ BTc,
                                               const float* __restrict__ bias,
                                               const float* __restrict__ lng,
                                               const float* __restrict__ lnb,
                                               float* __restrict__ C32,
                                               unsigned short* __restrict__ C16,
                                               int N, int strideA, int M) {
    __shared__ unsigned short Bls[128 * 128];   // 32 KB
    const int tid = threadIdx.x;
    const int w = tid >> 6, l = tid & 63;
    const int q = l >> 4;
    int r = blockIdx.x * 64 + w * 16 + (l & 15);
    if (r > N - 1) r = N - 1;

    bf16x8 afr[4];
    auto loadA = [&](int koff) {
        if (A16) {
            const unsigned short* A = (const unsigned short*)Ap;
#pragma unroll
            for (int c = 0; c < 4; ++c)
                afr[c] = *(const bf16x8*)(A + (size_t)r * strideA + koff + c * 32 + q * 8);
        } else {
            const float* A = (const float*)Ap;
            float av[4][8];
#pragma unroll
            for (int c = 0; c < 4; ++c) {
                const float* ap = A + (size_t)r * strideA + koff + c * 32 + q * 8;
                const float4 v0 = *(const float4*)ap;
                const float4 v1 = *(const float4*)(ap + 4);
                av[c][0] = v0.x; av[c][1] = v0.y; av[c][2] = v0.z; av[c][3] = v0.w;
                av[c][4] = v1.x; av[c][5] = v1.y; av[c][6] = v1.z; av[c][7] = v1.w;
            }
            if (LNM) {
                float s = 0.f;
#pragma unroll
                for (int c = 0; c < 4; ++c)
#pragma unroll
                    for (int j = 0; j < 8; ++j) s += av[c][j];
                s += __shfl_xor(s, 16, 64); s += __shfl_xor(s, 32, 64);
                const float mu = s * (1.f / 128.f);
                float vv = 0.f;
#pragma unroll
                for (int c = 0; c < 4; ++c)
#pragma unroll
                    for (int j = 0; j < 8; ++j) { const float dd = av[c][j] - mu; vv += dd * dd; }
                vv += __shfl_xor(vv, 16, 64); vv += __shfl_xor(vv, 32, 64);
                const float rs = rsqrtf(vv * (1.f / 128.f) + 1e-5f);
#pragma unroll
                for (int c = 0; c < 4; ++c) {
                    const int kb = c * 32 + q * 8;
                    const float4 g0 = *(const float4*)(lng + kb);
                    const float4 g1 = *(const float4*)(lng + kb + 4);
                    const float4 b0 = *(const float4*)(lnb + kb);
                    const float4 b1 = *(const float4*)(lnb + kb + 4);
                    const float gg[8] = {g0.x, g0.y, g0.z, g0.w, g1.x, g1.y, g1.z, g1.w};
                    const float bb[8] = {b0.x, b0.y, b0.z, b0.w, b1.x, b1.y, b1.z, b1.w};
#pragma unroll
                    for (int j = 0; j < 8; ++j)
                        av[c][j] = (av[c][j] - mu) * rs * gg[j] + bb[j];
                }
            }
#pragma unroll
            for (int c = 0; c < 4; ++c)
#pragma unroll
                for (int j = 0; j < 8; ++j) afr[c][j] = (short)f2bf(av[c][j]);
        }
    };

    f32x4 acc[8];
#pragma unroll
    for (int t = 0; t < 8; ++t) acc[t] = (f32x4){0.f, 0.f, 0.f, 0.f};

    if (!KM) loadA(0);

    const int rb = blockIdx.x * 64 + w * 16 + q * 4;
    auto epi = [&](int col0) {
#pragma unroll
        for (int t = 0; t < 8; ++t) {
            const int col = col0 + t * 16 + (l & 15);
            const float bv = BIAS ? bias[col] : 0.f;
#pragma unroll
            for (int rr = 0; rr < 4; ++rr) {
                const int row = rb + rr;
                if (row >= N) continue;
                float xv = acc[t][rr] + bv;
                if (ACC) xv += C32[(size_t)row * M + col];
                if (ACT == 1) xv = fmaxf(xv, 0.f);
                else if (ACT == 2) xv = 0.5f * xv * (1.f + erff(xv * 0.70710678118654752f));
                if (W32) C32[(size_t)row * M + col] = xv;
                if (W16) C16[(size_t)row * M + col] = f2bf(xv);
            }
        }
    };

#pragma unroll
    for (int rnd = 0; rnd < NR; ++rnd) {
        if (rnd) __syncthreads();
        const unsigned short* bsrc = BTc + (size_t)rnd * 16384;
#pragma unroll
        for (int i = 0; i < 8; ++i) {
            const int idx = i * 256 + tid;
            gl16(bsrc + (size_t)idx * 8, &Bls[idx * 8]);
        }
        if (KM) loadA(rnd * 128);
        __syncthreads();
#pragma unroll
        for (int c = 0; c < 4; ++c)
#pragma unroll
            for (int t = 0; t < 8; ++t) {
                const bf16x8 bfr = *(const bf16x8*)&Bls[((t * 4 + c) * 64 + l) * 8];
                acc[t] = __builtin_amdgcn_mfma_f32_16x16x32_bf16(afr[c], bfr, acc[t], 0, 0, 0);
            }
        if (!KM) {
            epi(rnd * 128);
#pragma unroll
            for (int t = 0; t < 8; ++t) acc[t] = (f32x4){0.f, 0.f, 0.f, 0.f};
        }
    }
    if (KM) epi(0);
}

// ------- GATv2: quarter-wave per edge, max-free softmax, SW pipeline --------
__global__ __launch_bounds__(256) void gat3_k(const unsigned short* __restrict__ X,
                                              const float* __restrict__ att,
                                              const float* __restrict__ gbias,
                                              const int* __restrict__ rowptr,
                                              const int* __restrict__ esrc,
                                              float* __restrict__ H, int n) {
    const int l = threadIdx.x & 63;
    const int node = blockIdx.x * 4 + (threadIdx.x >> 6);
    if (node >= n) return;
    const int q = l >> 4;
    const int d0 = (l & 15) * 8;

    float a8[8], xr[8], xs[8];
    {
        const float4 t0 = *(const float4*)&att[d0];
        const float4 t1 = *(const float4*)&att[d0 + 4];
        a8[0] = t0.x; a8[1] = t0.y; a8[2] = t0.z; a8[3] = t0.w;
        a8[4] = t1.x; a8[5] = t1.y; a8[6] = t1.z; a8[7] = t1.w;
        const bf16x8 uxs = *(const bf16x8*)&X[(size_t)node * 256 + d0];
        const bf16x8 uxr = *(const bf16x8*)&X[(size_t)node * 256 + 128 + d0];
#pragma unroll
        for (int j = 0; j < 8; ++j) {
            xs[j] = bf2f((unsigned short)uxs[j]);
            xr[j] = bf2f((unsigned short)uxr[j]);
        }
    }

    float sc = 0.f;
#pragma unroll
    for (int j = 0; j < 8; ++j) {
        const float e = xs[j] + xr[j];
        sc = fmaf(a8[j], fmaxf(e, 0.2f * e), sc);
    }
#pragma unroll
    for (int m = 1; m < 16; m <<= 1) sc += __shfl_xor(sc, m, 64);
    const float wself = __expf(sc);
    float dsum = (q == 0) ? wself : 0.f;
    float acc[8];
#pragma unroll
    for (int j = 0; j < 8; ++j) acc[j] = (q == 0) ? wself * xs[j] : 0.f;

    const int p1 = rowptr[node + 1];
    int p = rowptr[node] + q;
    bool v0 = p < p1, v1 = p + 4 < p1, v2 = p + 8 < p1;
    int i2 = v2 ? esrc[p + 8] : 0;
    bf16x8 u0, u1;
    if (v0) u0 = *(const bf16x8*)&X[(size_t)esrc[p] * 256 + d0];
    if (v1) u1 = *(const bf16x8*)&X[(size_t)esrc[p + 4] * 256 + d0];
    while (v0) {
        bf16x8 u2;
        if (v2) u2 = *(const bf16x8*)&X[(size_t)i2 * 256 + d0];
        const bool v3 = p + 12 < p1;
        const int i3 = v3 ? esrc[p + 12] : 0;

        float xl[8];
#pragma unroll
        for (int j = 0; j < 8; ++j) xl[j] = bf2f((unsigned short)u0[j]);
        float e_sc = 0.f;
#pragma unroll
        for (int j = 0; j < 8; ++j) {
            const float e = xl[j] + xr[j];
            e_sc = fmaf(a8[j], fmaxf(e, 0.2f * e), e_sc);
        }
#pragma unroll
        for (int m = 1; m < 16; m <<= 1) e_sc += __shfl_xor(e_sc, m, 64);
        const float wgt = __expf(e_sc);
        dsum += wgt;
#pragma unroll
        for (int j = 0; j < 8; ++j) acc[j] = fmaf(wgt, xl[j], acc[j]);

        u0 = u1; u1 = u2; i2 = i3;
        v0 = v1; v1 = v2; v2 = v3;
        p += 4;
    }

#pragma unroll
    for (int m = 16; m < 64; m <<= 1) {
        dsum += __shfl_xor(dsum, m, 64);
#pragma unroll
        for (int j = 0; j < 8; ++j) acc[j] += __shfl_xor(acc[j], m, 64);
    }

    if (q == 0) {
        const float inv = 1.f / dsum;
        const size_t o = (size_t)node * D + d0;
        float4 h0 = *(const float4*)&H[o];
        float4 h1 = *(const float4*)&H[o + 4];
        float hv[8] = {h0.x, h0.y, h0.z, h0.w, h1.x, h1.y, h1.z, h1.w};
#pragma unroll
        for (int j = 0; j < 8; ++j) hv[j] += acc[j] * inv + gbias[d0 + j];
        *(float4*)&H[o]     = make_float4(hv[0], hv[1], hv[2], hv[3]);
        *(float4*)&H[o + 4] = make_float4(hv[4], hv[5], hv[6], hv[7]);
    }
}

// ------- fused attention pooling: GEMM + gating + weighted H-sum ------------
// BTc = [Wa|Wb] chunked blobs; bias = [ba|bb]; atomic accumulate into red[132]
__global__ __launch_bounds__(256) void attnpool_k(const float* __restrict__ H,
                                                  const unsigned short* __restrict__ BTc,
                                                  const float* __restrict__ bias,
                                                  const float* __restrict__ Wc,
                                                  const float* __restrict__ bc,
                                                  float* __restrict__ red, int N) {
    __shared__ unsigned short Bls[128 * 128];   // 32 KB
    __shared__ float sacc[4][128];
    __shared__ float sdn[4];
    const int tid = threadIdx.x;
    const int w = tid >> 6, l = tid & 63;
    const int q = l >> 4, l15 = l & 15;
    const int rowbase = blockIdx.x * 64 + w * 16;
    int r = rowbase + l15;
    if (r > N - 1) r = N - 1;

    // H row fragments: fp32 kept for the weighted sum, bf16 for MFMA
    float av[4][8];
    bf16x8 afr[4];
#pragma unroll
    for (int c = 0; c < 4; ++c) {
        const float* ap = H + (size_t)r * D + c * 32 + q * 8;
        const float4 v0 = *(const float4*)ap;
        const float4 v1 = *(const float4*)(ap + 4);
        av[c][0] = v0.x; av[c][1] = v0.y; av[c][2] = v0.z; av[c][3] = v0.w;
        av[c][4] = v1.x; av[c][5] = v1.y; av[c][6] = v1.z; av[c][7] = v1.w;
#pragma unroll
        for (int j = 0; j < 8; ++j) afr[c][j] = (short)f2bf(av[c][j]);
    }

    float th[8][4];   // stashed tanh values (round 0)
    f32x4 acc[8];

#pragma unroll
    for (int rnd = 0; rnd < 2; ++rnd) {
        if (rnd) __syncthreads();
        const unsigned short* bsrc = BTc + (size_t)rnd * 16384;
#pragma unroll
        for (int i = 0; i < 8; ++i) {
            const int idx = i * 256 + tid;
            gl16(bsrc + (size_t)idx * 8, &Bls[idx * 8]);
        }
#pragma unroll
        for (int t = 0; t < 8; ++t) acc[t] = (f32x4){0.f, 0.f, 0.f, 0.f};
        __syncthreads();
#pragma unroll
        for (int c = 0; c < 4; ++c)
#pragma unroll
            for (int t = 0; t < 8; ++t) {
                const bf16x8 bfr = *(const bf16x8*)&Bls[((t * 4 + c) * 64 + l) * 8];
                acc[t] = __builtin_amdgcn_mfma_f32_16x16x32_bf16(afr[c], bfr, acc[t], 0, 0, 0);
            }
        if (rnd == 0) {
#pragma unroll
            for (int t = 0; t < 8; ++t) {
                const float bv = bias[t * 16 + l15];
#pragma unroll
                for (int rr = 0; rr < 4; ++rr) th[t][rr] = tanhf(acc[t][rr] + bv);
            }
        }
    }

    // gating dot: pa[rr] = sum_col tanh*sigmoid*Wc
    float pa[4] = {0.f, 0.f, 0.f, 0.f};
#pragma unroll
    for (int t = 0; t < 8; ++t) {
        const float bv = bias[128 + t * 16 + l15];
        const float wcv = Wc[t * 16 + l15];
#pragma unroll
        for (int rr = 0; rr < 4; ++rr) {
            const float sg = 1.f / (1.f + __expf(-(acc[t][rr] + bv)));
            pa[rr] = fmaf(th[t][rr] * sg, wcv, pa[rr]);
        }
    }
#pragma unroll
    for (int m = 1; m < 16; m <<= 1)
#pragma unroll
        for (int rr = 0; rr < 4; ++rr) pa[rr] += __shfl_xor(pa[rr], m, 64);

    const float bcv = bc[0];
    float wgt[4];
#pragma unroll
    for (int rr = 0; rr < 4; ++rr) {
        const int row = blockIdx.x * 64 + w * 16 + q * 4 + rr;
        wgt[rr] = (row < N) ? __expf(pa[rr] + bcv) : 0.f;
    }
    // denominator: sum over the wave's 16 rows
    float s = wgt[0] + wgt[1] + wgt[2] + wgt[3];
    s += __shfl_xor(s, 16, 64);
    s += __shfl_xor(s, 32, 64);
    if (l == 0) sdn[w] = s;

    // weight for MY H-row (row = rowbase + l15): from lane (l15>>2)*16, reg l15&3
    const int sl = ((l15 >> 2) << 4);
    float wv[4];
#pragma unroll
    for (int rr = 0; rr < 4; ++rr) wv[rr] = __shfl(wgt[rr], sl, 64);
    const int rsel = l15 & 3;
    float wm = (rsel == 0) ? wv[0] : (rsel == 1) ? wv[1] : (rsel == 2) ? wv[2] : wv[3];

    // weighted H sum: reduce over the 16 rows (l15 lanes)
#pragma unroll
    for (int c = 0; c < 4; ++c) {
        float pv[8];
#pragma unroll
        for (int j = 0; j < 8; ++j) pv[j] = wm * av[c][j];
#pragma unroll
        for (int m = 1; m < 16; m <<= 1)
#pragma unroll
            for (int j = 0; j < 8; ++j) pv[j] += __shfl_xor(pv[j], m, 64);
        if (l15 == 0) {
#pragma unroll
            for (int j = 0; j < 8; ++j) sacc[w][c * 32 + q * 8 + j] = pv[j];
        }
    }
    __syncthreads();
    if (tid < 128) {
        const float tot = sacc[0][tid] + sacc[1][tid] + sacc[2][tid] + sacc[3][tid];
        atomicAdd(&red[tid], tot);
    }
    if (tid == 0)
        atomicAdd(&red[128], sdn[0] + sdn[1] + sdn[2] + sdn[3]);
}

// ---------------- final: head from red ----------------
__global__ __launch_bounds__(128) void final_k(const float* __restrict__ red,
                                               const float* __restrict__ rho_W,
                                               const float* __restrict__ rho_b,
                                               const float* __restrict__ cls_W,
                                               const float* __restrict__ cls_b,
                                               float* __restrict__ out) {
    __shared__ float hp[128];
    __shared__ float hr[128];
    __shared__ float lg[4];
    const int t = threadIdx.x;
    hp[t] = red[t] / red[128];
    __syncthreads();
    float s = rho_b[t];
    for (int k = 0; k < 128; ++k) s = fmaf(hp[k], rho_W[k * 128 + t], s);
    hr[t] = fmaxf(s, 0.f);
    __syncthreads();
    if (t < 4) {
        float l = cls_b[t];
        for (int k = 0; k < 128; ++k) l = fmaf(hr[k], cls_W[k * 4 + t], l);
        lg[t] = l;
    }
    __syncthreads();
    if (t == 0) {
        float hz[4], S[4];
        for (int c = 0; c < 4; ++c) hz[c] = 1.f / (1.f + expf(-lg[c]));
        S[0] = 1.f - hz[0];
        for (int c = 1; c < 4; ++c) S[c] = S[c - 1] * (1.f - hz[c]);
        int am = 0; float bm = lg[0];
        for (int c = 1; c < 4; ++c) if (lg[c] > bm) { bm = lg[c]; am = c; }
        out[0] = hz[0]; out[1] = hz[1]; out[2] = hz[2]; out[3] = hz[3];
        out[4] = S[0];  out[5] = S[1];  out[6] = S[2];  out[7] = S[3];
        out[8] = (float)am;
        out[9] = lg[0]; out[10] = lg[1]; out[11] = lg[2]; out[12] = lg[3];
    }
}

// ---------------------------------------------------------------------------
static inline int cdiv(int a, int b) { return (a + b - 1) / b; }

extern "C" void kernel_launch(void* const* d_in, const int* in_sizes, int n_in,
                              void* d_out, int out_size, void* d_ws, size_t ws_size,
                              hipStream_t stream) {
    const float* x      = (const float*)d_in[0];
    const int*   ei     = (const int*)d_in[1];
    const float* emb_W  = (const float*)d_in[2];
    const float* emb_b  = (const float*)d_in[3];
    const float* ln1_g  = (const float*)d_in[4];
    const float* ln1_b  = (const float*)d_in[5];
    const float* gat_Wl = (const float*)d_in[6];
    const float* gat_bl = (const float*)d_in[7];
    const float* gat_Wr = (const float*)d_in[8];
    const float* gat_br = (const float*)d_in[9];
    const float* gat_att  = (const float*)d_in[10];
    const float* gat_bias = (const float*)d_in[11];
    const float* mlp_w1[NBLK] = {(const float*)d_in[12], (const float*)d_in[14], (const float*)d_in[16]};
    const float* mlp_w2[NBLK] = {(const float*)d_in[13], (const float*)d_in[15], (const float*)d_in[17]};
    const float* attn_Wa = (const float*)d_in[18];
    const float* attn_ba = (const float*)d_in[19];
    const float* attn_Wb = (const float*)d_in[20];
    const float* attn_bb = (const float*)d_in[21];
    const float* attn_Wc = (const float*)d_in[22];
    const float* attn_bc = (const float*)d_in[23];
    const float* rho_W   = (const float*)d_in[24];
    const float* rho_b   = (const float*)d_in[25];
    const float* cls_W   = (const float*)d_in[26];
    const float* cls_b   = (const float*)d_in[27];
    float* out = (float*)d_out;

    const int N = in_sizes[0] / 512;   // 50000
    const int E = in_sizes[1] / 2;     // 800000
    const int* src = ei;
    const int* dst = ei + E;
    const int gx = cdiv(N, 64);        // 782

    // ---- workspace layout ----
    char* base = (char*)d_ws;
    float* H = (float*)base;                                    // N*128 f32
    unsigned short* X = (unsigned short*)(H + (size_t)N * D);   // N*256 bf16 [xl|xr]
    unsigned short* T = X + (size_t)N * 256;                    // N*384 bf16
    float* red  = (float*)(T + (size_t)N * 384);                // 132
    float* sb   = red + 132;                                    // 4*256
    unsigned short* wbuf = (unsigned short*)(sb + 1024);        // 393216 bf16
    int* esrc   = (int*)(wbuf + 393216);                        // E
    int* deg    = esrc + E;                                     // N
    int* rowptr = deg + N;                                      // N+1
    int* fill   = rowptr + N + 1;                               // N
    int* bsum   = fill + N;                                     // 256

    unsigned short* embT = wbuf;                    // 4 rounds
    unsigned short* gatT = wbuf + 4 * 16384;        // 3 layers x 2 (Wl,Wr)
    unsigned short* w1T0 = gatT + 6 * 16384;
    unsigned short* w1T1 = w1T0 + 16384;
    unsigned short* w1T2 = w1T1 + 2 * 16384;
    unsigned short* w2T0 = w1T2 + 3 * 16384;
    unsigned short* w2T1 = w2T0 + 16384;
    unsigned short* w2T2 = w2T1 + 2 * 16384;
    unsigned short* attT = w2T2 + 3 * 16384;        // 2 blobs (Wa,Wb)
    unsigned short* w1T[NBLK] = {w1T0, w1T1, w1T2};
    unsigned short* w2T[NBLK] = {w2T0, w2T1, w2T2};

    // ---- CSR build ----
    const int nb = cdiv(N, 256);
    zero_k<<<cdiv(N, 256), 256, 0, stream>>>(deg, fill, red, N);
    hist_k<<<cdiv(E, 256), 256, 0, stream>>>(dst, deg, E);
    blockscan_k<<<nb, 256, 0, stream>>>(deg, rowptr, bsum, N);
    scansums_k<<<1, 256, 0, stream>>>(bsum, nb);
    addoff_k<<<nb, 256, 0, stream>>>(rowptr, bsum, N);
    scatter_k<<<cdiv(E, 256), 256, 0, stream>>>(src, dst, rowptr, fill, esrc, E);

    // ---- weight/bias prep ----
    {
        WPack p;
        int di = 0;
        for (int r = 0; r < 4; ++r)
            p.w[di++] = {emb_W + (size_t)r * 128 * 128, embT + (size_t)r * 16384, 128, 128};
        for (int i = 0; i < 3; ++i) {
            p.w[di++] = {gat_Wl + (size_t)i * 16384, gatT + (size_t)(2 * i) * 16384, 128, 128};
            p.w[di++] = {gat_Wr + (size_t)i * 16384, gatT + (size_t)(2 * i + 1) * 16384, 128, 128};
        }
        for (int i = 0; i < 3; ++i)
            p.w[di++] = {mlp_w1[i], w1T[i], 128, 128 * (i + 1)};
        for (int i = 0; i < 3; ++i)
            for (int r = 0; r <= i; ++r)
                p.w[di++] = {mlp_w2[i] + (size_t)r * 128 * 128, w2T[i] + (size_t)r * 16384, 128, 128};
        p.w[di++] = {attn_Wa, attT, 128, 128};
        p.w[di++] = {attn_Wb, attT + 16384, 128, 128};
        wprep_k<<<dim3(32, 21), 256, 0, stream>>>(p);
    }
    bcat_k<<<1, 256, 0, stream>>>(gat_bl, gat_br, attn_ba, attn_bb, sb);

    // ---- embedding: H = relu(x @ emb_W + emb_b), 4 k-rounds ----
    rgemm_k<4, true, 1, true, false, false, false, true, false>
        <<<gx, 256, 0, stream>>>(x, embT, emb_b, nullptr, nullptr,
                                 H, nullptr, N, 512, 128);

    // ---- 3 blocks ----
    for (int i = 0; i < NBLK; ++i) {
        rgemm_k<2, false, 0, true, false, true, false, false, true>
            <<<gx, 256, 0, stream>>>(H, gatT + (size_t)(2 * i) * 16384, sb + i * 256,
                                     ln1_g + i * D, ln1_b + i * D, nullptr, X, N, 128, 256);
        gat3_k<<<cdiv(N, 4), 256, 0, stream>>>(X, gat_att + i * D, gat_bias + i * D,
                                               rowptr, esrc, H, N);
        const int h = D * (i + 1);
        if (i == 0)
            rgemm_k<1, false, 2, false, false, false, false, false, true>
                <<<gx, 256, 0, stream>>>(H, w1T[i], nullptr, nullptr, nullptr,
                                         nullptr, T, N, 128, h);
        else if (i == 1)
            rgemm_k<2, false, 2, false, false, false, false, false, true>
                <<<gx, 256, 0, stream>>>(H, w1T[i], nullptr, nullptr, nullptr,
                                         nullptr, T, N, 128, h);
        else
            rgemm_k<3, false, 2, false, false, false, false, false, true>
                <<<gx, 256, 0, stream>>>(H, w1T[i], nullptr, nullptr, nullptr,
                                         nullptr, T, N, 128, h);
        if (i == 0)
            rgemm_k<1, true, 0, false, true, false, true, true, false>
                <<<gx, 256, 0, stream>>>(T, w2T[i], nullptr, nullptr, nullptr,
                                         H, nullptr, N, h, 128);
        else if (i == 1)
            rgemm_k<2, true, 0, false, true, false, true, true, false>
                <<<gx, 256, 0, stream>>>(T, w2T[i], nullptr, nullptr, nullptr,
                                         H, nullptr, N, h, 128);
        else
            rgemm_k<3, true, 0, false, true, false, true, true, false>
                <<<gx, 256, 0, stream>>>(T, w2T[i], nullptr, nullptr, nullptr,
                                         H, nullptr, N, h, 128);
    }

    // ---- fused gated attention pooling + head ----
    attnpool_k<<<gx, 256, 0, stream>>>(H, attT, sb + 3 * 256, attn_Wc, attn_bc, red, N);
    final_k<<<1, 128, 0, stream>>>(red, rho_W, rho_b, cls_W, cls_b, out);
}

// Round 8
// 657.322 us; speedup vs baseline: 1.3331x; 1.0681x over previous
//
#include <hip/hip_runtime.h>
#include <math.h>

// ---------------------------------------------------------------------------
// GraphMixer forward, round 8: row-local mega-fusion.
//   start_k : emb GEMM(4 k-rounds) + LN_0 + gatproj_0 -> H, X
//   bridge_k: mlp_i (col/k rounds, LDS transpose) + residual + LN_{i+1}
//             + gatproj_{i+1} -> H, X              (one dispatch per layer)
//   head_k  : mlp_2 + residual (H never written) + attnpool gating + atomics
//   gat3_k  : unchanged (quarter-wave edges, max-free softmax, SW pipeline)
// Main path: 8 dispatches (was 15). T buffer eliminated.
// ---------------------------------------------------------------------------

#define D 128
#define NBLK 3
#define STG_STRIDE 132   // 128 + 4 pad: breaks 16-way LDS bank aliasing

typedef __attribute__((ext_vector_type(8))) short bf16x8;
typedef __attribute__((ext_vector_type(4))) float f32x4;

static __device__ __forceinline__ float bf2f(unsigned short u) {
    union { unsigned i; float f; } c; c.i = ((unsigned)u) << 16; return c.f;
}
static __device__ __forceinline__ unsigned short f2bf(float f) {
    union { float f; unsigned i; } c; c.f = f;
    unsigned r = c.i + 0x7fff + ((c.i >> 16) & 1);
    return (unsigned short)(r >> 16);
}
static __device__ __forceinline__ void gl16(const unsigned short* g, unsigned short* l) {
    __builtin_amdgcn_global_load_lds((const __attribute__((address_space(1))) void*)g,
                                     (__attribute__((address_space(3))) void*)l, 16, 0, 0);
}
static __device__ __forceinline__ float gelu_f(float x) {
    return 0.5f * x * (1.f + erff(x * 0.70710678118654752f));
}

// ---------------- CSR build ----------------
__global__ void zero_k(int* deg, int* fill, float* red, int n) {
    int i = blockIdx.x * blockDim.x + threadIdx.x;
    if (i < n) { deg[i] = 0; fill[i] = 0; }
    if (i < 132) red[i] = 0.f;
}

__global__ void hist_k(const int* __restrict__ dst, int* __restrict__ deg, int E) {
    int e = blockIdx.x * blockDim.x + threadIdx.x;
    if (e < E) atomicAdd(&deg[dst[e]], 1);
}

__global__ __launch_bounds__(256) void blockscan_k(const int* __restrict__ deg,
                                                   int* __restrict__ rowptr,
                                                   int* __restrict__ bsum, int n) {
    __shared__ int tmp[256];
    const int tid = threadIdx.x;
    const int i = blockIdx.x * 256 + tid;
    int v = (i < n) ? deg[i] : 0;
    tmp[tid] = v;
    __syncthreads();
#pragma unroll
    for (int off = 1; off < 256; off <<= 1) {
        int t = (tid >= off) ? tmp[tid - off] : 0;
        __syncthreads();
        tmp[tid] += t;
        __syncthreads();
    }
    if (i < n) rowptr[i + 1] = tmp[tid];
    if (tid == 255) bsum[blockIdx.x] = tmp[255];
}

__global__ __launch_bounds__(256) void scansums_k(int* __restrict__ bsum, int nb) {
    __shared__ int tmp[256];
    const int tid = threadIdx.x;
    int v = (tid < nb) ? bsum[tid] : 0;
    tmp[tid] = v;
    __syncthreads();
#pragma unroll
    for (int off = 1; off < 256; off <<= 1) {
        int t = (tid >= off) ? tmp[tid - off] : 0;
        __syncthreads();
        tmp[tid] += t;
        __syncthreads();
    }
    if (tid < nb) bsum[tid] = tmp[tid];
}

__global__ __launch_bounds__(256) void addoff_k(int* __restrict__ rowptr,
                                                const int* __restrict__ bsum, int n) {
    int i = blockIdx.x * 256 + threadIdx.x;
    if (i == 0) rowptr[0] = 0;
    if (i < n && blockIdx.x > 0) rowptr[i + 1] += bsum[blockIdx.x - 1];
}

__global__ void scatter_k(const int* __restrict__ src, const int* __restrict__ dst,
                          const int* __restrict__ rowptr, int* __restrict__ fill,
                          int* __restrict__ esrc, int E) {
    int e = blockIdx.x * blockDim.x + threadIdx.x;
    if (e < E) {
        int d = dst[e];
        int pos = rowptr[d] + atomicAdd(&fill[d], 1);
        esrc[pos] = src[e];
    }
}

// ---------------- weight prep: [K][M] f32 -> chunked bf16 fragment order ----
struct WDesc { const float* s; unsigned short* d; int K; int M; };
struct WPack { WDesc w[21]; };

__global__ __launch_bounds__(256) void wprep_k(WPack p) {
    WDesc d = p.w[blockIdx.y];
    const int nc = d.K / 32;
    const int chunks = (d.M / 16) * nc * 64;
    for (int i = blockIdx.x * 256 + threadIdx.x; i < chunks; i += gridDim.x * 256) {
        const int l = i & 63;
        const int c = (i >> 6) % nc;
        const int t = i / (64 * nc);
        const int m = t * 16 + (l & 15);
        const int kb = c * 32 + ((l >> 4) & 3) * 8;
#pragma unroll
        for (int j = 0; j < 8; ++j)
            d.d[(size_t)i * 8 + j] = f2bf(d.s[(size_t)(kb + j) * d.M + m]);
    }
}

// stacked biases: sb[i][256] = [bl_i | br_i] (i<3), sb[3][256] = [ba | bb]
__global__ __launch_bounds__(256) void bcat_k(const float* bl, const float* br,
                                              const float* ba, const float* bb,
                                              float* sb) {
    const int t = threadIdx.x;
    for (int i = 0; i < 3; ++i)
        sb[i * 256 + t] = (t < 128) ? bl[i * 128 + t] : br[i * 128 + t - 128];
    sb[3 * 256 + t] = (t < 128) ? ba[t] : bb[t - 128];
}

// ======================= fused-kernel device pieces =========================
// All fused kernels: 256 threads, 64 rows/block.
//   w = tid>>6 (wave), l = tid&63, q = l>>4, l15 = l&15
//   wave w owns rows  rowbase + w*16 + l15   (A-layout lane->row)
//   C-layout: row = w*16 + q*4 + rr, col = t*16 + l15

// stage one 16384-elem (32KB) chunked blob into LDS
static __device__ __forceinline__ void stage_blob(const unsigned short* src,
                                                  unsigned short* wls, int tid) {
#pragma unroll
    for (int i = 0; i < 8; ++i) {
        const int idx = i * 256 + tid;
        gl16(src + (size_t)idx * 8, &wls[idx * 8]);
    }
}

// LN over a row held as av[4][8] across quads (lanes l, l^16, l^32, l^48)
static __device__ __forceinline__ void ln_row(float av[4][8], const float* lng,
                                              const float* lnb, int q) {
    float s = 0.f;
#pragma unroll
    for (int c = 0; c < 4; ++c)
#pragma unroll
        for (int j = 0; j < 8; ++j) s += av[c][j];
    s += __shfl_xor(s, 16, 64); s += __shfl_xor(s, 32, 64);
    const float mu = s * (1.f / 128.f);
    float vv = 0.f;
#pragma unroll
    for (int c = 0; c < 4; ++c)
#pragma unroll
        for (int j = 0; j < 8; ++j) { const float dd = av[c][j] - mu; vv += dd * dd; }
    vv += __shfl_xor(vv, 16, 64); vv += __shfl_xor(vv, 32, 64);
    const float rs = rsqrtf(vv * (1.f / 128.f) + 1e-5f);
#pragma unroll
    for (int c = 0; c < 4; ++c) {
        const int kb = c * 32 + q * 8;
        const float4 g0 = *(const float4*)(lng + kb);
        const float4 g1 = *(const float4*)(lng + kb + 4);
        const float4 b0 = *(const float4*)(lnb + kb);
        const float4 b1 = *(const float4*)(lnb + kb + 4);
        const float gg[8] = {g0.x, g0.y, g0.z, g0.w, g1.x, g1.y, g1.z, g1.w};
        const float bb[8] = {b0.x, b0.y, b0.z, b0.w, b1.x, b1.y, b1.z, b1.w};
#pragma unroll
        for (int j = 0; j < 8; ++j)
            av[c][j] = (av[c][j] - mu) * rs * gg[j] + bb[j];
    }
}

// gatproj: 2 col-rounds from xfr; writes X bf16 with bias (C-layout stores)
static __device__ __forceinline__ void gatproj(const bf16x8 xfr[4],
                                               const unsigned short* gatc,
                                               const float* sb256,
                                               unsigned short* X,
                                               unsigned short* wls,
                                               int rowbase, int w, int l, int N,
                                               int tid) {
    const int q = l >> 4, l15 = l & 15;
#pragma unroll
    for (int rnd = 0; rnd < 2; ++rnd) {
        __syncthreads();
        stage_blob(gatc + (size_t)rnd * 16384, wls, tid);
        f32x4 acc[8];
#pragma unroll
        for (int t = 0; t < 8; ++t) acc[t] = (f32x4){0.f, 0.f, 0.f, 0.f};
        __syncthreads();
#pragma unroll
        for (int c = 0; c < 4; ++c)
#pragma unroll
            for (int t = 0; t < 8; ++t) {
                const bf16x8 bfr = *(const bf16x8*)&wls[((t * 4 + c) * 64 + l) * 8];
                acc[t] = __builtin_amdgcn_mfma_f32_16x16x32_bf16(xfr[c], bfr, acc[t], 0, 0, 0);
            }
#pragma unroll
        for (int t = 0; t < 8; ++t) {
            const int col = rnd * 128 + t * 16 + l15;
            const float bv = sb256[col];
#pragma unroll
            for (int rr = 0; rr < 4; ++rr) {
                const int row = rowbase + w * 16 + q * 4 + rr;
                if (row < N) X[(size_t)row * 256 + col] = f2bf(acc[t][rr] + bv);
            }
        }
    }
}

// ---------------- start_k: emb + LN_0 + gatproj_0 ----------------
__global__ __launch_bounds__(256) void start_k(const float* __restrict__ x,
                                               const unsigned short* __restrict__ embc,
                                               const float* __restrict__ emb_b,
                                               const unsigned short* __restrict__ gatc,
                                               const float* __restrict__ lng,
                                               const float* __restrict__ lnb,
                                               const float* __restrict__ sb256,
                                               float* __restrict__ H,
                                               unsigned short* __restrict__ X, int N) {
    __shared__ unsigned short wls[16384];        // 32 KB
    __shared__ float stg[64 * STG_STRIDE];       // 33 KB
    const int tid = threadIdx.x;
    const int w = tid >> 6, l = tid & 63, q = l >> 4, l15 = l & 15;
    const int rowbase = blockIdx.x * 64;
    int r = rowbase + w * 16 + l15;
    const bool rv = r < N; if (!rv) r = N - 1;

    f32x4 accH[8];
#pragma unroll
    for (int t = 0; t < 8; ++t) accH[t] = (f32x4){0.f, 0.f, 0.f, 0.f};

#pragma unroll
    for (int rnd = 0; rnd < 4; ++rnd) {
        if (rnd) __syncthreads();
        stage_blob(embc + (size_t)rnd * 16384, wls, tid);
        bf16x8 afr[4];
#pragma unroll
        for (int c = 0; c < 4; ++c) {
            const float* ap = x + (size_t)r * 512 + rnd * 128 + c * 32 + q * 8;
            const float4 v0 = *(const float4*)ap;
            const float4 v1 = *(const float4*)(ap + 4);
            afr[c][0] = (short)f2bf(v0.x); afr[c][1] = (short)f2bf(v0.y);
            afr[c][2] = (short)f2bf(v0.z); afr[c][3] = (short)f2bf(v0.w);
            afr[c][4] = (short)f2bf(v1.x); afr[c][5] = (short)f2bf(v1.y);
            afr[c][6] = (short)f2bf(v1.z); afr[c][7] = (short)f2bf(v1.w);
        }
        __syncthreads();
#pragma unroll
        for (int c = 0; c < 4; ++c)
#pragma unroll
            for (int t = 0; t < 8; ++t) {
                const bf16x8 bfr = *(const bf16x8*)&wls[((t * 4 + c) * 64 + l) * 8];
                accH[t] = __builtin_amdgcn_mfma_f32_16x16x32_bf16(afr[c], bfr, accH[t], 0, 0, 0);
            }
    }

    // bias + relu, write H (C-layout), stage to LDS for transpose
    __syncthreads();
#pragma unroll
    for (int t = 0; t < 8; ++t) {
        const int col = t * 16 + l15;
        const float bv = emb_b[col];
#pragma unroll
        for (int rr = 0; rr < 4; ++rr) {
            const int row = rowbase + w * 16 + q * 4 + rr;
            const float hv = fmaxf(accH[t][rr] + bv, 0.f);
            if (row < N) H[(size_t)row * D + col] = hv;
            stg[(w * 16 + q * 4 + rr) * STG_STRIDE + col] = hv;
        }
    }
    __syncthreads();

    // read row-major, LN, bf16 frags
    float av[4][8];
#pragma unroll
    for (int c = 0; c < 4; ++c)
#pragma unroll
        for (int j = 0; j < 8; ++j)
            av[c][j] = stg[(w * 16 + l15) * STG_STRIDE + c * 32 + q * 8 + j];
    ln_row(av, lng, lnb, q);
    bf16x8 xfr[4];
#pragma unroll
    for (int c = 0; c < 4; ++c)
#pragma unroll
        for (int j = 0; j < 8; ++j) xfr[c][j] = (short)f2bf(av[c][j]);

    gatproj(xfr, gatc, sb256, X, wls, rowbase, w, l, N, tid);
}

// ---------------- bridge_k<NMR>: mlp + residual + LN + gatproj --------------
template <int NMR>
__global__ __launch_bounds__(256) void bridge_k(float* __restrict__ H,
                                                const unsigned short* __restrict__ w1c,
                                                const unsigned short* __restrict__ w2c,
                                                const unsigned short* __restrict__ gatc,
                                                const float* __restrict__ lng,
                                                const float* __restrict__ lnb,
                                                const float* __restrict__ sb256,
                                                unsigned short* __restrict__ X, int N) {
    __shared__ unsigned short wls[16384];        // 32 KB
    __shared__ float stg[64 * STG_STRIDE];       // 33 KB
    const int tid = threadIdx.x;
    const int w = tid >> 6, l = tid & 63, q = l >> 4, l15 = l & 15;
    const int rowbase = blockIdx.x * 64;
    int r = rowbase + w * 16 + l15;
    const bool rv = r < N; if (!rv) r = N - 1;

    // H row (A-layout)
    float av[4][8];
    bf16x8 afr[4];
#pragma unroll
    for (int c = 0; c < 4; ++c) {
        const float* ap = H + (size_t)r * D + c * 32 + q * 8;
        const float4 v0 = *(const float4*)ap;
        const float4 v1 = *(const float4*)(ap + 4);
        av[c][0] = v0.x; av[c][1] = v0.y; av[c][2] = v0.z; av[c][3] = v0.w;
        av[c][4] = v1.x; av[c][5] = v1.y; av[c][6] = v1.z; av[c][7] = v1.w;
#pragma unroll
        for (int j = 0; j < 8; ++j) afr[c][j] = (short)f2bf(av[c][j]);
    }

    f32x4 accH[8];
#pragma unroll
    for (int t = 0; t < 8; ++t) accH[t] = (f32x4){0.f, 0.f, 0.f, 0.f};

#pragma unroll
    for (int rnd = 0; rnd < NMR; ++rnd) {
        __syncthreads();
        stage_blob(w1c + (size_t)rnd * 16384, wls, tid);
        f32x4 accT[8];
#pragma unroll
        for (int t = 0; t < 8; ++t) accT[t] = (f32x4){0.f, 0.f, 0.f, 0.f};
        __syncthreads();
#pragma unroll
        for (int c = 0; c < 4; ++c)
#pragma unroll
            for (int t = 0; t < 8; ++t) {
                const bf16x8 bfr = *(const bf16x8*)&wls[((t * 4 + c) * 64 + l) * 8];
                accT[t] = __builtin_amdgcn_mfma_f32_16x16x32_bf16(afr[c], bfr, accT[t], 0, 0, 0);
            }
        __syncthreads();
        // gelu + transpose T via LDS
#pragma unroll
        for (int t = 0; t < 8; ++t)
#pragma unroll
            for (int rr = 0; rr < 4; ++rr)
                stg[(w * 16 + q * 4 + rr) * STG_STRIDE + t * 16 + l15] = gelu_f(accT[t][rr]);
        stage_blob(w2c + (size_t)rnd * 16384, wls, tid);
        __syncthreads();
        bf16x8 tfr[4];
#pragma unroll
        for (int c = 0; c < 4; ++c)
#pragma unroll
            for (int j = 0; j < 8; ++j)
                tfr[c][j] = (short)f2bf(stg[(w * 16 + l15) * STG_STRIDE + c * 32 + q * 8 + j]);
#pragma unroll
        for (int c = 0; c < 4; ++c)
#pragma unroll
            for (int t = 0; t < 8; ++t) {
                const bf16x8 bfr = *(const bf16x8*)&wls[((t * 4 + c) * 64 + l) * 8];
                accH[t] = __builtin_amdgcn_mfma_f32_16x16x32_bf16(tfr[c], bfr, accH[t], 0, 0, 0);
            }
    }

    // transpose accH, add residual -> H_new row-major
    __syncthreads();
#pragma unroll
    for (int t = 0; t < 8; ++t)
#pragma unroll
        for (int rr = 0; rr < 4; ++rr)
            stg[(w * 16 + q * 4 + rr) * STG_STRIDE + t * 16 + l15] = accH[t][rr];
    __syncthreads();
#pragma unroll
    for (int c = 0; c < 4; ++c)
#pragma unroll
        for (int j = 0; j < 8; ++j)
            av[c][j] += stg[(w * 16 + l15) * STG_STRIDE + c * 32 + q * 8 + j];

    // write H_new
    if (rv) {
#pragma unroll
        for (int c = 0; c < 4; ++c) {
            float* hp = H + (size_t)r * D + c * 32 + q * 8;
            *(float4*)hp       = make_float4(av[c][0], av[c][1], av[c][2], av[c][3]);
            *(float4*)(hp + 4) = make_float4(av[c][4], av[c][5], av[c][6], av[c][7]);
        }
    }

    // LN + gatproj
    ln_row(av, lng, lnb, q);
    bf16x8 xfr[4];
#pragma unroll
    for (int c = 0; c < 4; ++c)
#pragma unroll
        for (int j = 0; j < 8; ++j) xfr[c][j] = (short)f2bf(av[c][j]);

    gatproj(xfr, gatc, sb256, X, wls, rowbase, w, l, N, tid);
}

// ---------------- head_k: mlp_2 + residual + attnpool -----------------------
__global__ __launch_bounds__(256) void head_k(const float* __restrict__ H,
                                              const unsigned short* __restrict__ w1c,
                                              const unsigned short* __restrict__ w2c,
                                              const unsigned short* __restrict__ attc,
                                              const float* __restrict__ sb256,
                                              const float* __restrict__ Wc,
                                              const float* __restrict__ bc,
                                              float* __restrict__ red, int N) {
    __shared__ unsigned short wls[16384];        // 32 KB
    __shared__ float stg[64 * STG_STRIDE];       // 33 KB
    __shared__ float sacc[4][128];
    __shared__ float sdn[4];
    const int tid = threadIdx.x;
    const int w = tid >> 6, l = tid & 63, q = l >> 4, l15 = l & 15;
    const int rowbase = blockIdx.x * 64;
    int r = rowbase + w * 16 + l15;
    if (r > N - 1) r = N - 1;

    float av[4][8];
    bf16x8 afr[4];
#pragma unroll
    for (int c = 0; c < 4; ++c) {
        const float* ap = H + (size_t)r * D + c * 32 + q * 8;
        const float4 v0 = *(const float4*)ap;
        const float4 v1 = *(const float4*)(ap + 4);
        av[c][0] = v0.x; av[c][1] = v0.y; av[c][2] = v0.z; av[c][3] = v0.w;
        av[c][4] = v1.x; av[c][5] = v1.y; av[c][6] = v1.z; av[c][7] = v1.w;
#pragma unroll
        for (int j = 0; j < 8; ++j) afr[c][j] = (short)f2bf(av[c][j]);
    }

    f32x4 accH[8];
#pragma unroll
    for (int t = 0; t < 8; ++t) accH[t] = (f32x4){0.f, 0.f, 0.f, 0.f};

#pragma unroll
    for (int rnd = 0; rnd < 3; ++rnd) {
        __syncthreads();
        stage_blob(w1c + (size_t)rnd * 16384, wls, tid);
        f32x4 accT[8];
#pragma unroll
        for (int t = 0; t < 8; ++t) accT[t] = (f32x4){0.f, 0.f, 0.f, 0.f};
        __syncthreads();
#pragma unroll
        for (int c = 0; c < 4; ++c)
#pragma unroll
            for (int t = 0; t < 8; ++t) {
                const bf16x8 bfr = *(const bf16x8*)&wls[((t * 4 + c) * 64 + l) * 8];
                accT[t] = __builtin_amdgcn_mfma_f32_16x16x32_bf16(afr[c], bfr, accT[t], 0, 0, 0);
            }
        __syncthreads();
#pragma unroll
        for (int t = 0; t < 8; ++t)
#pragma unroll
            for (int rr = 0; rr < 4; ++rr)
                stg[(w * 16 + q * 4 + rr) * STG_STRIDE + t * 16 + l15] = gelu_f(accT[t][rr]);
        stage_blob(w2c + (size_t)rnd * 16384, wls, tid);
        __syncthreads();
        bf16x8 tfr[4];
#pragma unroll
        for (int c = 0; c < 4; ++c)
#pragma unroll
            for (int j = 0; j < 8; ++j)
                tfr[c][j] = (short)f2bf(stg[(w * 16 + l15) * STG_STRIDE + c * 32 + q * 8 + j]);
#pragma unroll
        for (int c = 0; c < 4; ++c)
#pragma unroll
            for (int t = 0; t < 8; ++t) {
                const bf16x8 bfr = *(const bf16x8*)&wls[((t * 4 + c) * 64 + l) * 8];
                accH[t] = __builtin_amdgcn_mfma_f32_16x16x32_bf16(tfr[c], bfr, accH[t], 0, 0, 0);
            }
    }

    // transpose + residual -> H_new (row-major regs; NOT written to global)
    __syncthreads();
#pragma unroll
    for (int t = 0; t < 8; ++t)
#pragma unroll
        for (int rr = 0; rr < 4; ++rr)
            stg[(w * 16 + q * 4 + rr) * STG_STRIDE + t * 16 + l15] = accH[t][rr];
    __syncthreads();
#pragma unroll
    for (int c = 0; c < 4; ++c)
#pragma unroll
        for (int j = 0; j < 8; ++j)
            av[c][j] += stg[(w * 16 + l15) * STG_STRIDE + c * 32 + q * 8 + j];
#pragma unroll
    for (int c = 0; c < 4; ++c)
#pragma unroll
        for (int j = 0; j < 8; ++j) afr[c][j] = (short)f2bf(av[c][j]);

    // attn GEMM: round 0 = Wa (tanh stash), round 1 = Wb
    float th[8][4];
    f32x4 acc[8];
#pragma unroll
    for (int rnd = 0; rnd < 2; ++rnd) {
        __syncthreads();
        stage_blob(attc + (size_t)rnd * 16384, wls, tid);
#pragma unroll
        for (int t = 0; t < 8; ++t) acc[t] = (f32x4){0.f, 0.f, 0.f, 0.f};
        __syncthreads();
#pragma unroll
        for (int c = 0; c < 4; ++c)
#pragma unroll
            for (int t = 0; t < 8; ++t) {
                const bf16x8 bfr = *(const bf16x8*)&wls[((t * 4 + c) * 64 + l) * 8];
                acc[t] = __builtin_amdgcn_mfma_f32_16x16x32_bf16(afr[c], bfr, acc[t], 0, 0, 0);
            }
        if (rnd == 0) {
#pragma unroll
            for (int t = 0; t < 8; ++t) {
                const float bv = sb256[t * 16 + l15];
#pragma unroll
                for (int rr = 0; rr < 4; ++rr) th[t][rr] = tanhf(acc[t][rr] + bv);
            }
        }
    }

    // gating dot over cols
    float pa[4] = {0.f, 0.f, 0.f, 0.f};
#pragma unroll
    for (int t = 0; t < 8; ++t) {
        const float bv = sb256[128 + t * 16 + l15];
        const float wcv = Wc[t * 16 + l15];
#pragma unroll
        for (int rr = 0; rr < 4; ++rr) {
            const float sg = 1.f / (1.f + __expf(-(acc[t][rr] + bv)));
            pa[rr] = fmaf(th[t][rr] * sg, wcv, pa[rr]);
        }
    }
#pragma unroll
    for (int m = 1; m < 16; m <<= 1)
#pragma unroll
        for (int rr = 0; rr < 4; ++rr) pa[rr] += __shfl_xor(pa[rr], m, 64);

    const float bcv = bc[0];
    float wgt[4];
#pragma unroll
    for (int rr = 0; rr < 4; ++rr) {
        const int row = rowbase + w * 16 + q * 4 + rr;
        wgt[rr] = (row < N) ? __expf(pa[rr] + bcv) : 0.f;
    }
    float s = wgt[0] + wgt[1] + wgt[2] + wgt[3];
    s += __shfl_xor(s, 16, 64);
    s += __shfl_xor(s, 32, 64);
    if (l == 0) sdn[w] = s;

    // weight for my row (rowbase + w*16 + l15): from lane (l15>>2)*16, reg l15&3
    const int sl = ((l15 >> 2) << 4);
    float wv[4];
#pragma unroll
    for (int rr = 0; rr < 4; ++rr) wv[rr] = __shfl(wgt[rr], sl, 64);
    const int rsel = l15 & 3;
    const float wm = (rsel == 0) ? wv[0] : (rsel == 1) ? wv[1] : (rsel == 2) ? wv[2] : wv[3];

#pragma unroll
    for (int c = 0; c < 4; ++c) {
        float pv[8];
#pragma unroll
        for (int j = 0; j < 8; ++j) pv[j] = wm * av[c][j];
#pragma unroll
        for (int m = 1; m < 16; m <<= 1)
#pragma unroll
            for (int j = 0; j < 8; ++j) pv[j] += __shfl_xor(pv[j], m, 64);
        if (l15 == 0) {
#pragma unroll
            for (int j = 0; j < 8; ++j) sacc[w][c * 32 + q * 8 + j] = pv[j];
        }
    }
    __syncthreads();
    if (tid < 128) {
        const float tot = sacc[0][tid] + sacc[1][tid] + sacc[2][tid] + sacc[3][tid];
        atomicAdd(&red[tid], tot);
    }
    if (tid == 0)
        atomicAdd(&red[128], sdn[0] + sdn[1] + sdn[2] + sdn[3]);
}

// ------- GATv2: quarter-wave per edge, max-free softmax, SW pipeline --------
__global__ __launch_bounds__(256) void gat3_k(const unsigned short* __restrict__ X,
                                              const float* __restrict__ att,
                                              const float* __restrict__ gbias,
                                              const int* __restrict__ rowptr,
                                              const int* __restrict__ esrc,
                                              float* __restrict__ H, int n) {
    const int l = threadIdx.x & 63;
    const int node = blockIdx.x * 4 + (threadIdx.x >> 6);
    if (node >= n) return;
    const int q = l >> 4;
    const int d0 = (l & 15) * 8;

    float a8[8], xr[8], xs[8];
    {
        const float4 t0 = *(const float4*)&att[d0];
        const float4 t1 = *(const float4*)&att[d0 + 4];
        a8[0] = t0.x; a8[1] = t0.y; a8[2] = t0.z; a8[3] = t0.w;
        a8[4] = t1.x; a8[5] = t1.y; a8[6] = t1.z; a8[7] = t1.w;
        const bf16x8 uxs = *(const bf16x8*)&X[(size_t)node * 256 + d0];
        const bf16x8 uxr = *(const bf16x8*)&X[(size_t)node * 256 + 128 + d0];
#pragma unroll
        for (int j = 0; j < 8; ++j) {
            xs[j] = bf2f((unsigned short)uxs[j]);
            xr[j] = bf2f((unsigned short)uxr[j]);
        }
    }

    float sc = 0.f;
#pragma unroll
    for (int j = 0; j < 8; ++j) {
        const float e = xs[j] + xr[j];
        sc = fmaf(a8[j], fmaxf(e, 0.2f * e), sc);
    }
#pragma unroll
    for (int m = 1; m < 16; m <<= 1) sc += __shfl_xor(sc, m, 64);
    const float wself = __expf(sc);
    float dsum = (q == 0) ? wself : 0.f;
    float acc[8];
#pragma unroll
    for (int j = 0; j < 8; ++j) acc[j] = (q == 0) ? wself * xs[j] : 0.f;

    const int p1 = rowptr[node + 1];
    int p = rowptr[node] + q;
    bool v0 = p < p1, v1 = p + 4 < p1, v2 = p + 8 < p1;
    int i2 = v2 ? esrc[p + 8] : 0;
    bf16x8 u0, u1;
    if (v0) u0 = *(const bf16x8*)&X[(size_t)esrc[p] * 256 + d0];
    if (v1) u1 = *(const bf16x8*)&X[(size_t)esrc[p + 4] * 256 + d0];
    while (v0) {
        bf16x8 u2;
        if (v2) u2 = *(const bf16x8*)&X[(size_t)i2 * 256 + d0];
        const bool v3 = p + 12 < p1;
        const int i3 = v3 ? esrc[p + 12] : 0;

        float xl[8];
#pragma unroll
        for (int j = 0; j < 8; ++j) xl[j] = bf2f((unsigned short)u0[j]);
        float e_sc = 0.f;
#pragma unroll
        for (int j = 0; j < 8; ++j) {
            const float e = xl[j] + xr[j];
            e_sc = fmaf(a8[j], fmaxf(e, 0.2f * e), e_sc);
        }
#pragma unroll
        for (int m = 1; m < 16; m <<= 1) e_sc += __shfl_xor(e_sc, m, 64);
        const float wgt = __expf(e_sc);
        dsum += wgt;
#pragma unroll
        for (int j = 0; j < 8; ++j) acc[j] = fmaf(wgt, xl[j], acc[j]);

        u0 = u1; u1 = u2; i2 = i3;
        v0 = v1; v1 = v2; v2 = v3;
        p += 4;
    }

#pragma unroll
    for (int m = 16; m < 64; m <<= 1) {
        dsum += __shfl_xor(dsum, m, 64);
#pragma unroll
        for (int j = 0; j < 8; ++j) acc[j] += __shfl_xor(acc[j], m, 64);
    }

    if (q == 0) {
        const float inv = 1.f / dsum;
        const size_t o = (size_t)node * D + d0;
        float4 h0 = *(const float4*)&H[o];
        float4 h1 = *(const float4*)&H[o + 4];
        float hv[8] = {h0.x, h0.y, h0.z, h0.w, h1.x, h1.y, h1.z, h1.w};
#pragma unroll
        for (int j = 0; j < 8; ++j) hv[j] += acc[j] * inv + gbias[d0 + j];
        *(float4*)&H[o]     = make_float4(hv[0], hv[1], hv[2], hv[3]);
        *(float4*)&H[o + 4] = make_float4(hv[4], hv[5], hv[6], hv[7]);
    }
}

// ---------------- final: head from red ----------------
__global__ __launch_bounds__(128) void final_k(const float* __restrict__ red,
                                               const float* __restrict__ rho_W,
                                               const float* __restrict__ rho_b,
                                               const float* __restrict__ cls_W,
                                               const float* __restrict__ cls_b,
                                               float* __restrict__ out) {
    __shared__ float hp[128];
    __shared__ float hr[128];
    __shared__ float lg[4];
    const int t = threadIdx.x;
    hp[t] = red[t] / red[128];
    __syncthreads();
    float s = rho_b[t];
    for (int k = 0; k < 128; ++k) s = fmaf(hp[k], rho_W[k * 128 + t], s);
    hr[t] = fmaxf(s, 0.f);
    __syncthreads();
    if (t < 4) {
        float l = cls_b[t];
        for (int k = 0; k < 128; ++k) l = fmaf(hr[k], cls_W[k * 4 + t], l);
        lg[t] = l;
    }
    __syncthreads();
    if (t == 0) {
        float hz[4], S[4];
        for (int c = 0; c < 4; ++c) hz[c] = 1.f / (1.f + expf(-lg[c]));
        S[0] = 1.f - hz[0];
        for (int c = 1; c < 4; ++c) S[c] = S[c - 1] * (1.f - hz[c]);
        int am = 0; float bm = lg[0];
        for (int c = 1; c < 4; ++c) if (lg[c] > bm) { bm = lg[c]; am = c; }
        out[0] = hz[0]; out[1] = hz[1]; out[2] = hz[2]; out[3] = hz[3];
        out[4] = S[0];  out[5] = S[1];  out[6] = S[2];  out[7] = S[3];
        out[8] = (float)am;
        out[9] = lg[0]; out[10] = lg[1]; out[11] = lg[2]; out[12] = lg[3];
    }
}

// ---------------------------------------------------------------------------
static inline int cdiv(int a, int b) { return (a + b - 1) / b; }

extern "C" void kernel_launch(void* const* d_in, const int* in_sizes, int n_in,
                              void* d_out, int out_size, void* d_ws, size_t ws_size,
                              hipStream_t stream) {
    const float* x      = (const float*)d_in[0];
    const int*   ei     = (const int*)d_in[1];
    const float* emb_W  = (const float*)d_in[2];
    const float* emb_b  = (const float*)d_in[3];
    const float* ln1_g  = (const float*)d_in[4];
    const float* ln1_b  = (const float*)d_in[5];
    const float* gat_Wl = (const float*)d_in[6];
    const float* gat_bl = (const float*)d_in[7];
    const float* gat_Wr = (const float*)d_in[8];
    const float* gat_br = (const float*)d_in[9];
    const float* gat_att  = (const float*)d_in[10];
    const float* gat_bias = (const float*)d_in[11];
    const float* mlp_w1[NBLK] = {(const float*)d_in[12], (const float*)d_in[14], (const float*)d_in[16]};
    const float* mlp_w2[NBLK] = {(const float*)d_in[13], (const float*)d_in[15], (const float*)d_in[17]};
    const float* attn_Wa = (const float*)d_in[18];
    const float* attn_ba = (const float*)d_in[19];
    const float* attn_Wb = (const float*)d_in[20];
    const float* attn_bb = (const float*)d_in[21];
    const float* attn_Wc = (const float*)d_in[22];
    const float* attn_bc = (const float*)d_in[23];
    const float* rho_W   = (const float*)d_in[24];
    const float* rho_b   = (const float*)d_in[25];
    const float* cls_W   = (const float*)d_in[26];
    const float* cls_b   = (const float*)d_in[27];
    float* out = (float*)d_out;

    const int N = in_sizes[0] / 512;   // 50000
    const int E = in_sizes[1] / 2;     // 800000
    const int* src = ei;
    const int* dst = ei + E;
    const int gx = cdiv(N, 64);        // 782

    // ---- workspace layout ----
    char* base = (char*)d_ws;
    float* H = (float*)base;                                    // N*128 f32
    unsigned short* X = (unsigned short*)(H + (size_t)N * D);   // N*256 bf16 [xl|xr]
    float* red  = (float*)(X + (size_t)N * 256);                // 132
    float* sb   = red + 132;                                    // 4*256
    unsigned short* wbuf = (unsigned short*)(sb + 1024);        // 393216 bf16
    int* esrc   = (int*)(wbuf + 393216);                        // E
    int* deg    = esrc + E;                                     // N
    int* rowptr = deg + N;                                      // N+1
    int* fill   = rowptr + N + 1;                               // N
    int* bsum   = fill + N;                                     // 256

    unsigned short* embT = wbuf;                    // 4 blobs
    unsigned short* gatT = wbuf + 4 * 16384;        // 3 layers x 2 (Wl,Wr)
    unsigned short* w1T0 = gatT + 6 * 16384;
    unsigned short* w1T1 = w1T0 + 16384;
    unsigned short* w1T2 = w1T1 + 2 * 16384;
    unsigned short* w2T0 = w1T2 + 3 * 16384;
    unsigned short* w2T1 = w2T0 + 16384;
    unsigned short* w2T2 = w2T1 + 2 * 16384;
    unsigned short* attT = w2T2 + 3 * 16384;        // 2 blobs (Wa,Wb)
    unsigned short* w1T[NBLK] = {w1T0, w1T1, w1T2};
    unsigned short* w2T[NBLK] = {w2T0, w2T1, w2T2};

    // ---- CSR build ----
    const int nb = cdiv(N, 256);
    zero_k<<<cdiv(N, 256), 256, 0, stream>>>(deg, fill, red, N);
    hist_k<<<cdiv(E, 256), 256, 0, stream>>>(dst, deg, E);
    blockscan_k<<<nb, 256, 0, stream>>>(deg, rowptr, bsum, N);
    scansums_k<<<1, 256, 0, stream>>>(bsum, nb);
    addoff_k<<<nb, 256, 0, stream>>>(rowptr, bsum, N);
    scatter_k<<<cdiv(E, 256), 256, 0, stream>>>(src, dst, rowptr, fill, esrc, E);

    // ---- weight/bias prep ----
    {
        WPack p;
        int di = 0;
        for (int r = 0; r < 4; ++r)
            p.w[di++] = {emb_W + (size_t)r * 128 * 128, embT + (size_t)r * 16384, 128, 128};
        for (int i = 0; i < 3; ++i) {
            p.w[di++] = {gat_Wl + (size_t)i * 16384, gatT + (size_t)(2 * i) * 16384, 128, 128};
            p.w[di++] = {gat_Wr + (size_t)i * 16384, gatT + (size_t)(2 * i + 1) * 16384, 128, 128};
        }
        for (int i = 0; i < 3; ++i)
            p.w[di++] = {mlp_w1[i], w1T[i], 128, 128 * (i + 1)};
        for (int i = 0; i < 3; ++i)
            for (int r = 0; r <= i; ++r)
                p.w[di++] = {mlp_w2[i] + (size_t)r * 128 * 128, w2T[i] + (size_t)r * 16384, 128, 128};
        p.w[di++] = {attn_Wa, attT, 128, 128};
        p.w[di++] = {attn_Wb, attT + 16384, 128, 128};
        wprep_k<<<dim3(32, 21), 256, 0, stream>>>(p);
    }
    bcat_k<<<1, 256, 0, stream>>>(gat_bl, gat_br, attn_ba, attn_bb, sb);

    // ---- main path: 8 dispatches ----
    start_k<<<gx, 256, 0, stream>>>(x, embT, emb_b, gatT, ln1_g, ln1_b, sb, H, X, N);
    gat3_k<<<cdiv(N, 4), 256, 0, stream>>>(X, gat_att, gat_bias, rowptr, esrc, H, N);

    bridge_k<1><<<gx, 256, 0, stream>>>(H, w1T[0], w2T[0], gatT + 2 * 16384,
                                        ln1_g + D, ln1_b + D, sb + 256, X, N);
    gat3_k<<<cdiv(N, 4), 256, 0, stream>>>(X, gat_att + D, gat_bias + D, rowptr, esrc, H, N);

    bridge_k<2><<<gx, 256, 0, stream>>>(H, w1T[1], w2T[1], gatT + 4 * 16384,
                                        ln1_g + 2 * D, ln1_b + 2 * D, sb + 512, X, N);
    gat3_k<<<cdiv(N, 4), 256, 0, stream>>>(X, gat_att + 2 * D, gat_bias + 2 * D, rowptr, esrc, H, N);

    head_k<<<gx, 256, 0, stream>>>(H, w1T[2], w2T[2], attT, sb + 3 * 256,
                                   attn_Wc, attn_bc, red, N);
    final_k<<<1, 128, 0, stream>>>(red, rho_W, rho_b, cls_W, cls_b, out);
}